// Round 11
// baseline (1327.039 us; speedup 1.0000x reference)
//
#include <hip/hip_runtime.h>
#include <math.h>

// ---------------- static config ----------------
#define NF 32
#define NPATHS 34

typedef __attribute__((ext_vector_type(8))) short bf16x8;
typedef __attribute__((ext_vector_type(4))) float f32x4;
typedef __attribute__((ext_vector_type(2))) float f32x2;

__device__ __forceinline__ unsigned short f2bf(float v){
  unsigned u = __float_as_uint(v);
  u += 0x7fffu + ((u>>16)&1u);
  return (unsigned short)(u>>16);
}
__device__ __forceinline__ float bf2f(unsigned short h){
  return __uint_as_float(((unsigned)h)<<16);
}

struct PathTab { int l1[NPATHS]; int l2[NPATHS]; int l3[NPATHS]; };
constexpr PathTab mkpaths(){
  PathTab t{}; int n=0;
  for(int a=0;a<=3;a++)for(int b=0;b<=3;b++)for(int c=0;c<=3;c++){
    int lo = a>b ? a-b : b-a;
    if(c>=lo && c<=a+b){ t.l1[n]=a; t.l2[n]=b; t.l3[n]=c; n++; }
  }
  return t;
}
constexpr PathTab PT = mkpaths();

// ---------------- compile-time Wigner-3j (exact replica of reference math) ----------------
struct FactT { double v[22]; };
constexpr FactT mkfactT(){ FactT f{}; f.v[0]=1.0; for(int i=1;i<22;i++) f.v[i]=f.v[i-1]*(double)i; return f; }
constexpr FactT FT = mkfactT();
constexpr double cfact(int n){ return FT.v[n]; }

constexpr double csqrt(double x){
  if(x<=0.0) return 0.0;
  double g = x<1.0 ? 1.0 : x;
  for(int i=0;i<40;i++) g=0.5*(g+x/g);
  return g;
}

constexpr double su2cg(int j1,int j2,int j3,int m1,int m2){
  int m3=m1+m2;
  if(m3<-j3||m3>j3) return 0.0;
  double pref = (double)(2*j3+1)*cfact(j3+j1-j2)*cfact(j3-j1+j2)*cfact(j1+j2-j3)/cfact(j1+j2+j3+1);
  pref *= cfact(j3+m3)*cfact(j3-m3)*cfact(j1-m1)*cfact(j1+m1)*cfact(j2-m2)*cfact(j2+m2);
  pref = csqrt(pref);
  int k0=0; if(j2-j3-m1>k0)k0=j2-j3-m1; if(j1-j3+m2>k0)k0=j1-j3+m2;
  int k1=j1+j2-j3; if(j1-m1<k1)k1=j1-m1; if(j2+m2<k1)k1=j2+m2;
  double s=0.0;
  for(int k=k0;k<=k1;k++){
    double d = cfact(k)*cfact(j1+j2-j3-k)*cfact(j1-m1-k)*cfact(j2+m2-k)*cfact(j3-j2+m1+k)*cfact(j3-j1-m2+k);
    s += (k&1)? -1.0/d : 1.0/d;
  }
  return pref*s;
}

struct ccd { double x, y; };
constexpr ccd cqval(int l,int r,int col){
  const double is2 = 0.70710678118654752440;
  double re=0.0, im=0.0;
  if (r<l){ if (col==2*l-r) re=is2; else if (col==r) im=-is2; }
  else if (r==l){ if (col==l) re=1.0; }
  else { double s = ((r-l)&1)? -1.0:1.0;
         if (col==r) re=s*is2; else if (col==2*l-r) im=s*is2; }
  ccd v{re,im};
  switch(l&3){           // multiply by (-i)^l
    case 1: return ccd{ v.y, -v.x };
    case 2: return ccd{-v.x, -v.y };
    case 3: return ccd{-v.y,  v.x };
    default: return v;
  }
}

constexpr double w3entry(int l1,int l2,int l3,int i,int j,int k){
  double re=0.0;
  for(int a=0;a<2*l1+1;a++){
    ccd qa=cqval(l1,a,i); if(qa.x==0.0&&qa.y==0.0) continue;
    for(int b=0;b<2*l2+1;b++){
      ccd qb=cqval(l2,b,j); if(qb.x==0.0&&qb.y==0.0) continue;
      int m1=a-l1, m2=b-l2, m3=m1+m2;
      if(m3<-l3||m3>l3) continue;
      int c=m3+l3;
      double cg=su2cg(l1,l2,l3,m1,m2); if(cg==0.0) continue;
      ccd qc=cqval(l3,c,k); qc.y=-qc.y;   // conj
      if(qc.x==0.0&&qc.y==0.0) continue;
      ccd ab{qa.x*qb.x-qa.y*qb.y, qa.x*qb.y+qa.y*qb.x};
      re += cg*(ab.x*qc.x - ab.y*qc.y);
    }
  }
  return re;
}

template<int L1,int L2,int L3> struct W3Arr { float v[(2*L1+1)*(2*L2+1)*(2*L3+1)]; };
template<int L1,int L2,int L3> constexpr W3Arr<L1,L2,L3> mkW3(double scale){
  W3Arr<L1,L2,L3> r{};
  for(int i=0;i<2*L1+1;i++)
    for(int j=0;j<2*L2+1;j++)
      for(int k=0;k<2*L3+1;k++)
        r.v[(i*(2*L2+1)+j)*(2*L3+1)+k] = (float)(w3entry(L1,L2,L3,i,j,k)*scale);
  return r;
}
template<int L1,int L2,int L3> constexpr W3Arr<L1,L2,L3> W3V = mkW3<L1,L2,L3>(1.0);
template<int L1,int L2,int L3> constexpr W3Arr<L1,L2,L3> W3N = mkW3<L1,L2,L3>(1.0/csqrt(2.0*L3+1.0));

// SH recursion scales (replica of reference _sh_scales, float64 like numpy)
struct SCt { double sc2, sc3; };
constexpr SCt mksc(){
  double v0=0.2,v1=-0.6,v2=0.7;
  double nv=csqrt(v0*v0+v1*v1+v2*v2);
  double s3=csqrt(3.0);
  double y1[3]={s3*v0/nv, s3*v1/nv, s3*v2/nv};
  double t2[5]={0,0,0,0,0}; double n2=0.0;
  for(int c=0;c<5;c++){
    double s=0.0;
    for(int a=0;a<3;a++)for(int b=0;b<3;b++) s += w3entry(1,1,2,a,b,c)*y1[a]*y1[b];
    t2[c]=s; n2+=s*s;
  }
  double sc2=csqrt(5.0)/csqrt(n2);
  double y2[5]={sc2*t2[0],sc2*t2[1],sc2*t2[2],sc2*t2[3],sc2*t2[4]};
  double n3=0.0;
  for(int c=0;c<7;c++){
    double s=0.0;
    for(int a=0;a<5;a++)for(int b=0;b<3;b++) s += w3entry(2,1,3,a,b,c)*y2[a]*y1[b];
    n3+=s*s;
  }
  double sc3=csqrt(7.0)/csqrt(n3);
  return SCt{sc2,sc3};
}
constexpr SCt SCV = mksc();

// ---------------- scalar template-unrolled TP with literal W3J (node kernels + SH) ----------------
template<bool NORM,int l1,int l2,int l3,int A,int B,int C>
__device__ __forceinline__ void w3term(const float* __restrict__ x, const float* __restrict__ y,
                                       float rv, float* __restrict__ acc){
  constexpr float w = NORM ? W3N<l1,l2,l3>.v[(A*(2*l2+1)+B)*(2*l3+1)+C]
                           : W3V<l1,l2,l3>.v[(A*(2*l2+1)+B)*(2*l3+1)+C];
  if constexpr (w!=0.0f)
    acc[l3*l3+C] = fmaf(w, x[l1*l1+A]*y[l2*l2+B]*rv, acc[l3*l3+C]);
}
template<bool NORM,int l1,int l2,int l3,int A,int B,int C>
__device__ __forceinline__ void w3loopC(const float* x,const float* y,float rv,float* acc){
  if constexpr (C<2*l3+1){
    w3term<NORM,l1,l2,l3,A,B,C>(x,y,rv,acc);
    w3loopC<NORM,l1,l2,l3,A,B,C+1>(x,y,rv,acc);
  }
}
template<bool NORM,int l1,int l2,int l3,int A,int B>
__device__ __forceinline__ void w3loopB(const float* x,const float* y,float rv,float* acc){
  if constexpr (B<2*l2+1){
    w3loopC<NORM,l1,l2,l3,A,B,0>(x,y,rv,acc);
    w3loopB<NORM,l1,l2,l3,A,B+1>(x,y,rv,acc);
  }
}
template<bool NORM,int l1,int l2,int l3,int A>
__device__ __forceinline__ void w3loopA(const float* x,const float* y,float rv,float* acc){
  if constexpr (A<2*l1+1){
    w3loopB<NORM,l1,l2,l3,A,0>(x,y,rv,acc);
    w3loopA<NORM,l1,l2,l3,A+1>(x,y,rv,acc);
  }
}

template<int P>
__device__ __forceinline__ void tpn_paths(const float* x,const float* y,float* o){
  if constexpr (P<NPATHS){
    constexpr int l1=PT.l1[P], l2=PT.l2[P], l3=PT.l3[P];
    w3loopA<true,l1,l2,l3,0>(x,y,1.0f,o);
    tpn_paths<P+1>(x,y,o);
  }
}

// scalar-only node TP: l3=0 paths (l,l,0) only
__device__ __forceinline__ float tpn_scalar(const float* x,const float* y){
  float o[1]={0.f};
  w3loopA<true,0,0,0,0>(x,y,1.0f,o);
  w3loopA<true,1,1,0,0>(x,y,1.0f,o);
  w3loopA<true,2,2,0,0>(x,y,1.0f,o);
  w3loopA<true,3,3,0,0>(x,y,1.0f,o);
  return o[0];
}

// ---------------- packed-pair (two edges per thread, f32x2 -> v_pk_fma_f32) TP ----------------
template<int l1,int l2,int l3,int A,int B>
constexpr bool anyNZ(){
  for(int c=0;c<2*l3+1;c++)
    if(W3V<l1,l2,l3>.v[(A*(2*l2+1)+B)*(2*l3+1)+c]!=0.0f) return true;
  return false;
}
template<int l1,int l2,int l3,int A,int B,int C>
__device__ __forceinline__ void w3C2(const f32x2 p, f32x2* __restrict__ S){
  constexpr float w = W3V<l1,l2,l3>.v[(A*(2*l2+1)+B)*(2*l3+1)+C];
  if constexpr (w!=0.0f) S[C] = p*w + S[C];
  if constexpr (C+1<2*l3+1) w3C2<l1,l2,l3,A,B,C+1>(p,S);
}
template<int l1,int l2,int l3,int A,int B>
__device__ __forceinline__ void w3B2(const f32x2* __restrict__ x,const f32x2* __restrict__ y,
                                     f32x2* __restrict__ S){
  if constexpr (anyNZ<l1,l2,l3,A,B>()){
    f32x2 p = x[l1*l1+A]*y[l2*l2+B];
    w3C2<l1,l2,l3,A,B,0>(p,S);
  }
  if constexpr (B+1<2*l2+1) w3B2<l1,l2,l3,A,B+1>(x,y,S);
}
template<int l1,int l2,int l3,int A>
__device__ __forceinline__ void w3A2(const f32x2* __restrict__ x,const f32x2* __restrict__ y,
                                     f32x2* __restrict__ S){
  w3B2<l1,l2,l3,A,0>(x,y,S);
  if constexpr (A+1<2*l1+1) w3A2<l1,l2,l3,A+1>(x,y,S);
}
// R21 layout: rws element (P,f,le) at u16 index (P*32+f)*18 + le.
// rp = rws + f*18 + le0; path P -> rp[P*576] (edge A) and rp[P*576+4] (edge B, le1=le0+4).
// f-lanes stride 36B = 9 dwords, gcd(9,32)=1 -> all 32 banks; half-wave pairing 2-way (free).
template<bool L0,int P>
__device__ __forceinline__ void tp2(const f32x2* __restrict__ x,const f32x2* __restrict__ y,
                                    const unsigned short* __restrict__ rp,
                                    f32x2* __restrict__ acc){
  if constexpr (P<NPATHS){
    constexpr int l1=PT.l1[P], l2=PT.l2[P], l3=PT.l3[P];
    if constexpr (!(L0 && l1!=0)){
      f32x2 S[2*l3+1];
      #pragma unroll
      for(int c=0;c<2*l3+1;c++) S[c]=(f32x2){0.f,0.f};
      w3A2<l1,l2,l3,0>(x,y,S);
      f32x2 rv = { bf2f(rp[P*576]), bf2f(rp[P*576+4]) };
      #pragma unroll
      for(int c=0;c<2*l3+1;c++) acc[l3*l3+c] = rv*S[c] + acc[l3*l3+c];
    }
    tp2<L0,P+1>(x,y,rp,acc);
  }
}

// ---------------- CSR build: degree count, scan, fill ----------------
__global__ __launch_bounds__(256) void k_count(
    const int* __restrict__ rcv, int* __restrict__ deg, int E)
{
  int e=blockIdx.x*256+threadIdx.x;
  if(e>=E) return;
  atomicAdd(&deg[rcv[e]],1);
}

#define SCAN_PER 32
__global__ __launch_bounds__(1024) void k_scan(
    const int* __restrict__ deg, int* __restrict__ row,
    int* __restrict__ cur, int N)
{
  __shared__ int part[1024];
  int t=threadIdx.x;
  int per=(N+1023)/1024; if(per>SCAN_PER) per=SCAN_PER;
  int base=t*per;
  int loc[SCAN_PER];
  int s=0;
  for(int i=0;i<per;i++){ int idx=base+i; int v=(idx<N)? deg[idx]:0; loc[i]=s; s+=v; }
  part[t]=s;
  __syncthreads();
  for(int off=1;off<1024;off<<=1){
    int v=(t>=off)? part[t-off]:0;
    __syncthreads();
    part[t]+=v;
    __syncthreads();
  }
  int ex=(t==0)?0:part[t-1];
  for(int i=0;i<per;i++){
    int idx=base+i;
    if(idx<N){ int r=ex+loc[i]; row[idx]=r; cur[idx]=r; }
  }
  if(t==1023) row[N]=part[1023];
}

__global__ __launch_bounds__(256) void k_fill(
    const int* __restrict__ rcv, int* __restrict__ cur,
    int* __restrict__ eid, int E)
{
  int e=blockIdx.x*256+threadIdx.x;
  if(e>=E) return;
  int pos=atomicAdd(&cur[rcv[e]],1);
  eid[pos]=e;
}

// ---------------- per-edge geometry (receiver-sorted order): SH + radial basis ----------------
__global__ __launch_bounds__(256) void k_edge_setup(
    const float* __restrict__ vec, const int* __restrict__ snd,
    const int* __restrict__ rcv, const int* __restrict__ eid,
    float* __restrict__ Y, float* __restrict__ rad,
    int* __restrict__ snd_s, int* __restrict__ rcv_s, int E)
{
  int j = blockIdx.x*256+threadIdx.x;
  if (j>=E) return;
  int e = eid[j];
  snd_s[j]=snd[e];
  rcv_s[j]=rcv[e];
  float vx=vec[3*e], vy=vec[3*e+1], vz=vec[3*e+2];
  float r=sqrtf(vx*vx+vy*vy+vz*vz);
  float inv=1.0f/fmaxf(r,1e-9f);
  float y[16];
  y[0]=1.0f;
  const float s3=1.7320508075688772f;
  y[1]=s3*vx*inv; y[2]=s3*vy*inv; y[3]=s3*vz*inv;
  constexpr float sc2=(float)SCV.sc2, sc3=(float)SCV.sc3;
  {
    float t[16];
    #pragma unroll
    for(int c=0;c<16;c++) t[c]=0.f;
    w3loopA<false,1,1,2,0>(y,y,1.0f,t);
    #pragma unroll
    for(int c=0;c<5;c++) y[4+c]=sc2*t[4+c];
    w3loopA<false,2,1,3,0>(y,y,1.0f,t);
    #pragma unroll
    for(int c=0;c<7;c++) y[9+c]=sc3*t[9+c];
  }
  float4* Yp=(float4*)(Y+(size_t)j*16);
  Yp[0]=make_float4(y[0],y[1],y[2],y[3]);
  Yp[1]=make_float4(y[4],y[5],y[6],y[7]);
  Yp[2]=make_float4(y[8],y[9],y[10],y[11]);
  Yp[3]=make_float4(y[12],y[13],y[14],y[15]);
  float x = r*0.2f;
  float env=0.f;
  if (x<1.0f){
    float x2=x*x; float x4=x2*x2; float x5=x4*x;
    env = 1.0f - 21.0f*x5 + 35.0f*x5*x - 15.0f*x5*x2;
  }
  const float cb = 0.632455532033675866f; // sqrt(2/5)
  float base = inv*env*cb;
  #pragma unroll
  for(int n=1;n<=8;n++)
    rad[(size_t)j*8 + n-1] = base*sinf(3.14159265358979323846f * x * (float)n);
}

// ---------------- layer-0 hlin directly from scalar embedding (bf16) ----------------
__global__ __launch_bounds__(256) void k_embed16(
    const float* __restrict__ embed, const float* __restrict__ up0,
    const int* __restrict__ z, unsigned short* __restrict__ hl16, int N)
{
  int t=blockIdx.x*256+threadIdx.x;
  int n=t>>5, g=t&31;
  if(n>=N) return;
  const float* ep=embed+z[n]*32;
  float a=0.f;
  #pragma unroll 8
  for(int f=0;f<32;f++) a=fmaf(ep[f],up0[(f<<5)+g],a);
  bf16x8 o0={(short)f2bf(a),0,0,0,0,0,0,0};
  bf16x8 o1={0,0,0,0,0,0,0,0};
  bf16x8* op=(bf16x8*)(hl16+(size_t)n*512+g*16);
  op[0]=o0; op[1]=o1;
}

// ---------------- weight prep: cast+transpose both w2, and comb = post0@sel0 ----------------
__global__ __launch_bounds__(256) void k_prep(
    const float* __restrict__ w2a, const float* __restrict__ w2b,
    unsigned short* __restrict__ ta, unsigned short* __restrict__ tb,
    const float* __restrict__ post0, const float* __restrict__ sel0,
    float* __restrict__ comb)
{
  int t=blockIdx.x*256+threadIdx.x;
  const int C2=2*1088*64;
  if(t<C2){
    const float* src = (t<1088*64)? w2a : w2b;
    unsigned short* dst = (t<1088*64)? ta : tb;
    int u = (t<1088*64)? t : t-1088*64;
    int c=u>>6, k=u&63;
    dst[(size_t)c*64+k]=f2bf(src[(size_t)k*1088+c]);
  } else {
    int u=t-C2;
    if(u<10*4096){
      int z=u>>12, r=u&4095;
      int l=r>>10, e=(r>>5)&31, g=r&31;
      const float* pp=post0+l*1024+e*32;
      const float* sp=sel0+(size_t)z*4096+l*1024;
      float a=0.f;
      #pragma unroll 8
      for(int f=0;f<32;f++) a=fmaf(pp[f], sp[f*32+g], a);
      comb[(size_t)z*4096 + l*1024 + e*32 + g]=a;
    }
  }
}

// ---------------- FUSED: radial MLP (phase 0) + MFMA rw-GEMM (LDS) + packed-pair TP + in-block reduce ----------------
// R23 verified best (583.7). R24: absorb k_radial into phase 0 (fused is only 47% VALU-busy;
// radial math fills the bubbles) and delete the 16MB hid round-trip per layer + 2 dispatches.
// Phase 0: 16 threads/edge compute the 2-layer radial MLP (identical fma order / silu / f2bf
// as the old k_radial -> bit-identical hid values) into hid_s (stride 72 u16: 16B-aligned
// fragments, <=2-way banks). h1 intermediate lives in the rws region (dead until phase 1).
// Phase 1 A-fragments become 16B LDS reads of hid_s.
template<bool L0>
__global__ __launch_bounds__(256,3) void k_tp_fused(
    const unsigned short* __restrict__ hlin, const float* __restrict__ Y,
    const float* __restrict__ rad, const float* __restrict__ w0g,
    const float* __restrict__ w1g, const unsigned short* __restrict__ w2t,
    const int* __restrict__ snd_s, const int* __restrict__ rcv_s,
    float* __restrict__ agg, int ecnt)
{
  constexpr int NT  = L0 ? 8 : 68;      // 16-wide col tiles of the rw GEMM
  constexpr int PD  = L0 ? 4 : 34;      // P dim of rws
  constexpr int RWSU = PD*32*18;        // u16 in the rw strip
  constexpr int LMU  = 8704*2;          // u16 backing 512x17 f32 lmsg (stride-17 pad)
  constexpr int LDSU = RWSU > LMU ? RWSU : LMU;
  __shared__ unsigned short rws[LDSU] __attribute__((aligned(16)));
  __shared__ unsigned short hid_s[16*72] __attribute__((aligned(16)));
  __shared__ int r16v[16];
  int tid=threadIdx.x;
  int lane=tid&63, wave=tid>>6;
  int m16=lane&15, quad=lane>>4;
  int el0=blockIdx.x*16;
  int f=tid&31;
  int hb=(tid>>5)&1;
  int le_base = wave + hb*8;
  int el_s0 = el0 + le_base;
  int el_s1 = el0 + le_base + 4;
  bool actA = el_s0<ecnt, okB = el_s1<ecnt;
  int s0 = actA ? snd_s[el_s0] : 0;
  int s1 = okB  ? snd_s[el_s1] : 0;
  if(tid<16) r16v[tid] = (el0+tid<ecnt) ? rcv_s[el0+tid] : -1;
  // ---- phase 0: radial MLP for this block's 16 edges -> hid_s (bf16) ----
  {
    int le0i = tid>>4, tj = tid&15, j4 = tj*4;
    int el = el0 + le0i;
    float rv[8];
    if (el < ecnt){
      const float4* rp4=(const float4*)(rad+(size_t)el*8);
      float4 ra=rp4[0], rb=rp4[1];
      rv[0]=ra.x; rv[1]=ra.y; rv[2]=ra.z; rv[3]=ra.w;
      rv[4]=rb.x; rv[5]=rb.y; rv[6]=rb.z; rv[7]=rb.w;
    } else {
      #pragma unroll
      for(int i=0;i<8;i++) rv[i]=0.f;
    }
    float* h1s = (float*)rws;           // [16][68] f32; dead before phase 1 writes rws
    #pragma unroll
    for(int jj=0;jj<4;jj++){
      int j=j4+jj;
      float a=0.f;
      #pragma unroll
      for(int i=0;i<8;i++) a=fmaf(rv[i], w0g[i*64+j], a);
      h1s[le0i*68+j]=a/(1.f+__expf(-a));
    }
    __syncthreads();
    #pragma unroll
    for(int jj=0;jj<4;jj++){
      int j=j4+jj;
      float a=0.f;
      #pragma unroll 16
      for(int i=0;i<64;i++) a=fmaf(h1s[le0i*68+i], w1g[i*64+j], a);
      hid_s[le0i*72+j]=f2bf(a/(1.f+__expf(-a)));
    }
    __syncthreads();
  }
  // ---- phase 1: rw GEMM (A from hid_s LDS), store [P][f][le] as packed bf16 pairs ----
  {
    bf16x8 a0 = *(const bf16x8*)(hid_s + m16*72 + quad*8);
    bf16x8 a1 = *(const bf16x8*)(hid_s + m16*72 + 32 + quad*8);
    #pragma unroll 2
    for(int nt=wave; nt<NT; nt+=4){
      int col = nt*16 + m16;
      bf16x8 b0 = *(const bf16x8*)(w2t + (size_t)col*64 + quad*8);
      bf16x8 b1 = *(const bf16x8*)(w2t + (size_t)col*64 + 32 + quad*8);
      f32x4 acc = (f32x4){0.f,0.f,0.f,0.f};
      acc = __builtin_amdgcn_mfma_f32_16x16x32_bf16(a0,b0,acc,0,0,0);
      acc = __builtin_amdgcn_mfma_f32_16x16x32_bf16(a1,b1,acc,0,0,0);
      int fc = col&31, P = col>>5;
      unsigned w0 = (unsigned)f2bf(acc[0]) | ((unsigned)f2bf(acc[1])<<16);
      unsigned w1 = (unsigned)f2bf(acc[2]) | ((unsigned)f2bf(acc[3])<<16);
      unsigned* wp = (unsigned*)(rws + (size_t)(P*32+fc)*18 + quad*4);
      wp[0]=w0; wp[1]=w1;
    }
  }
  __syncthreads();
  // ---- phase 2: packed-pair TP for edges (el_s0, el_s1) ----
  size_t jA = actA ? (size_t)el_s0 : 0;
  size_t jB = okB  ? (size_t)el_s1 : 0;
  f32x2 hs[16];
  if constexpr (L0){
    hs[0] = (f32x2){ bf2f(hlin[(size_t)s0*512 + f*16]),
                     bf2f(hlin[(size_t)s1*512 + f*16]) };
  } else {
    const bf16x8* hA = (const bf16x8*)(hlin + (size_t)s0*512 + f*16);
    const bf16x8* hB = (const bf16x8*)(hlin + (size_t)s1*512 + f*16);
    bf16x8 ha0=hA[0], ha1=hA[1], hb0=hB[0], hb1=hB[1];
    #pragma unroll
    for(int c=0;c<8;c++){
      hs[c]   = (f32x2){ bf2f((unsigned short)ha0[c]), bf2f((unsigned short)hb0[c]) };
      hs[8+c] = (f32x2){ bf2f((unsigned short)ha1[c]), bf2f((unsigned short)hb1[c]) };
    }
  }
  f32x2 yv[16];
  {
    const float4* yA=(const float4*)(Y+jA*16);
    const float4* yB=(const float4*)(Y+jB*16);
    float4 a0=yA[0],a1=yA[1],a2=yA[2],a3=yA[3];
    float4 b0=yB[0],b1=yB[1],b2=yB[2],b3=yB[3];
    yv[0]=(f32x2){a0.x,b0.x}; yv[1]=(f32x2){a0.y,b0.y}; yv[2]=(f32x2){a0.z,b0.z}; yv[3]=(f32x2){a0.w,b0.w};
    yv[4]=(f32x2){a1.x,b1.x}; yv[5]=(f32x2){a1.y,b1.y}; yv[6]=(f32x2){a1.z,b1.z}; yv[7]=(f32x2){a1.w,b1.w};
    yv[8]=(f32x2){a2.x,b2.x}; yv[9]=(f32x2){a2.y,b2.y}; yv[10]=(f32x2){a2.z,b2.z}; yv[11]=(f32x2){a2.w,b2.w};
    yv[12]=(f32x2){a3.x,b3.x}; yv[13]=(f32x2){a3.y,b3.y}; yv[14]=(f32x2){a3.z,b3.z}; yv[15]=(f32x2){a3.w,b3.w};
  }
  const unsigned short* rp = rws + f*18 + le_base;
  f32x2 acc[16];
  #pragma unroll
  for(int c=0;c<16;c++) acc[c]=(f32x2){0.f,0.f};
  tp2<L0,0>(hs,yv,rp,acc);
  // ---- phase 3: stage f32 messages in LDS (stride-17 rows), segment-reduce, atomicAdd ----
  __syncthreads();                       // all tp2 LDS reads done; safe to overwrite
  float* lm = (float*)rws;               // lmsg[(le*32+f)*17 + c]
  if(actA){
    #pragma unroll
    for(int c=0;c<16;c++) lm[(le_base*32+f)*17+c] = acc[c].x*0.0625f;
  }
  if(okB){
    #pragma unroll
    for(int c=0;c<16;c++) lm[((le_base+4)*32+f)*17+c] = acc[c].y*0.0625f;
  }
  __syncthreads();
  #pragma unroll
  for(int s=tid; s<512; s+=256){
    int ff=s>>4, cc=s&15;
    float run=0.f; int cur=-1;
    #pragma unroll
    for(int le=0; le<16; le++){
      int rr = r16v[le];
      if(rr != cur){
        if(cur >= 0) atomicAdd(agg + (size_t)cur*512 + s, run);
        run = 0.f; cur = rr;
      }
      if(rr >= 0) run += lm[(le*32+ff)*17 + cc];
    }
    if(cur >= 0) atomicAdd(agg + (size_t)cur*512 + s, run);
  }
}

// ---------------- fused layer-0 node chain: lin(comb)+tp_node(pb0)+pblin0+readout+up1->hl16 ----------------
__global__ __launch_bounds__(256) void k_node0(
    const float* __restrict__ agg, const float* __restrict__ combw,
    const float* __restrict__ pb0, const float* __restrict__ pblin0,
    const float* __restrict__ ro0, const float* __restrict__ res1,
    const float* __restrict__ up1, const int* __restrict__ z,
    float* __restrict__ e0, float* __restrict__ resid,
    unsigned short* __restrict__ hl16, int N)
{
  __shared__ float sh1[8*512] __attribute__((aligned(16)));
  __shared__ float sh2[8*512] __attribute__((aligned(16)));
  int tid=threadIdx.x;
  int n0=tid>>5, g=tid&31;
  int n=blockIdx.x*8+n0;
  bool act=(n<N);
  int zz = act? z[n] : 0;
  if(act){
    const float* wp = combw + (size_t)zz*4096;
    const float* ip = agg + (size_t)n*512;
    float A[16];
    #pragma unroll
    for(int c=0;c<16;c++) A[c]=0.f;
    #pragma unroll 8
    for(int f=0;f<NF;f++){
      const float4* xp=(const float4*)(ip+f*16);
      float4 x0=xp[0],x1=xp[1],x2=xp[2],x3=xp[3];
      float w0v=wp[(f<<5)+g],w1v=wp[1024+(f<<5)+g],w2v=wp[2048+(f<<5)+g],w3v=wp[3072+(f<<5)+g];
      A[0]=fmaf(x0.x,w0v,A[0]);  A[1]=fmaf(x0.y,w1v,A[1]);  A[2]=fmaf(x0.z,w1v,A[2]);  A[3]=fmaf(x0.w,w1v,A[3]);
      A[4]=fmaf(x1.x,w2v,A[4]);  A[5]=fmaf(x1.y,w2v,A[5]);  A[6]=fmaf(x1.z,w2v,A[6]);  A[7]=fmaf(x1.w,w2v,A[7]);
      A[8]=fmaf(x2.x,w2v,A[8]);  A[9]=fmaf(x2.y,w3v,A[9]);  A[10]=fmaf(x2.z,w3v,A[10]);A[11]=fmaf(x2.w,w3v,A[11]);
      A[12]=fmaf(x3.x,w3v,A[12]);A[13]=fmaf(x3.y,w3v,A[13]);A[14]=fmaf(x3.z,w3v,A[14]);A[15]=fmaf(x3.w,w3v,A[15]);
    }
    float B2[16],B3[16];
    #pragma unroll
    for(int c=0;c<16;c++){ B2[c]=0.f; B3[c]=0.f; }
    tpn_paths<0>(A,A,B2);
    tpn_paths<0>(B2,A,B3);
    float wa=pb0[zz*96+g], wb=pb0[zz*96+32+g], wc=pb0[zz*96+64+g];
    #pragma unroll
    for(int c=0;c<16;c++) sh1[n0*512+g*16+c]=wa*A[c]+wb*B2[c]+wc*B3[c];
  }
  __syncthreads();
  // pblin0 mix (cross-f from sh1) -> feats -> sh2
  if(act){
    float ft[16];
    #pragma unroll
    for(int c=0;c<16;c++) ft[c]=0.f;
    const float* wp=pblin0;
    #pragma unroll 8
    for(int f=0;f<NF;f++){
      const float4* xp=(const float4*)(sh1+n0*512+f*16);
      float4 x0=xp[0],x1=xp[1],x2=xp[2],x3=xp[3];
      float w0v=wp[(f<<5)+g],w1v=wp[1024+(f<<5)+g],w2v=wp[2048+(f<<5)+g],w3v=wp[3072+(f<<5)+g];
      ft[0]=fmaf(x0.x,w0v,ft[0]);  ft[1]=fmaf(x0.y,w1v,ft[1]);  ft[2]=fmaf(x0.z,w1v,ft[2]);  ft[3]=fmaf(x0.w,w1v,ft[3]);
      ft[4]=fmaf(x1.x,w2v,ft[4]);  ft[5]=fmaf(x1.y,w2v,ft[5]);  ft[6]=fmaf(x1.z,w2v,ft[6]);  ft[7]=fmaf(x1.w,w2v,ft[7]);
      ft[8]=fmaf(x2.x,w2v,ft[8]);  ft[9]=fmaf(x2.y,w3v,ft[9]);  ft[10]=fmaf(x2.z,w3v,ft[10]);ft[11]=fmaf(x2.w,w3v,ft[11]);
      ft[12]=fmaf(x3.x,w3v,ft[12]);ft[13]=fmaf(x3.y,w3v,ft[13]);ft[14]=fmaf(x3.z,w3v,ft[14]);ft[15]=fmaf(x3.w,w3v,ft[15]);
    }
    #pragma unroll
    for(int c=0;c<16;c++) sh2[n0*512+g*16+c]=ft[c];
  }
  __syncthreads();
  if(act){
    // readout: resid + e0 from feats scalar channel
    const float* wp=res1+(size_t)zz*1024;
    float a=0.f;
    #pragma unroll 8
    for(int f=0;f<32;f++) a=fmaf(sh2[n0*512+f*16], wp[(f<<5)+g], a);
    resid[(size_t)n*32+g]=a;
    if(g==0){
      float b=0.f;
      #pragma unroll 8
      for(int f=0;f<32;f++) b=fmaf(sh2[n0*512+f*16], ro0[f], b);
      e0[n]=b;
    }
    // up1 mix -> bf16 hl16 (layer-1 hlin)
    float acc[16];
    #pragma unroll
    for(int c=0;c<16;c++) acc[c]=0.f;
    const float* wp2=up1;
    #pragma unroll 8
    for(int f=0;f<NF;f++){
      const float4* xp=(const float4*)(sh2+n0*512+f*16);
      float4 x0=xp[0],x1=xp[1],x2=xp[2],x3=xp[3];
      float w0v=wp2[(f<<5)+g],w1v=wp2[1024+(f<<5)+g],w2v=wp2[2048+(f<<5)+g],w3v=wp2[3072+(f<<5)+g];
      acc[0]=fmaf(x0.x,w0v,acc[0]);  acc[1]=fmaf(x0.y,w1v,acc[1]);  acc[2]=fmaf(x0.z,w1v,acc[2]);  acc[3]=fmaf(x0.w,w1v,acc[3]);
      acc[4]=fmaf(x1.x,w2v,acc[4]);  acc[5]=fmaf(x1.y,w2v,acc[5]);  acc[6]=fmaf(x1.z,w2v,acc[6]);  acc[7]=fmaf(x1.w,w2v,acc[7]);
      acc[8]=fmaf(x2.x,w2v,acc[8]);  acc[9]=fmaf(x2.y,w3v,acc[9]);  acc[10]=fmaf(x2.z,w3v,acc[10]);acc[11]=fmaf(x2.w,w3v,acc[11]);
      acc[12]=fmaf(x3.x,w3v,acc[12]);acc[13]=fmaf(x3.y,w3v,acc[13]);acc[14]=fmaf(x3.z,w3v,acc[14]);acc[15]=fmaf(x3.w,w3v,acc[15]);
    }
    bf16x8 o0,o1;
    #pragma unroll
    for(int c=0;c<8;c++){ o0[c]=(short)f2bf(acc[c]); o1[c]=(short)f2bf(acc[8+c]); }
    bf16x8* op=(bf16x8*)(hl16+(size_t)n*512+g*16);
    op[0]=o0; op[1]=o1;
  }
}

// ---------------- fused layer-1 node chain: lin(post1)+tp_node_sc(pb1)+pblin1+final ----------------
__global__ __launch_bounds__(256) void k_node1(
    const float* __restrict__ agg, const float* __restrict__ post1,
    const float* __restrict__ pb1, const float* __restrict__ pblin1,
    const int* __restrict__ z, const float* __restrict__ resid,
    const float* __restrict__ e0a, const float* __restrict__ ro1a,
    const float* __restrict__ ro1b, float* __restrict__ out, int N)
{
  __shared__ float sh[8*32];
  __shared__ float sh2[8*32];
  __shared__ float red[8];
  int tid=threadIdx.x;
  int n0=tid>>5, g=tid&31;
  int n=blockIdx.x*8+n0;
  bool act=(n<N);
  if(act){
    const float* wp=post1;
    const float* ip=agg+(size_t)n*512;
    float A[16];
    #pragma unroll
    for(int c=0;c<16;c++) A[c]=0.f;
    #pragma unroll 8
    for(int f=0;f<NF;f++){
      const float4* xp=(const float4*)(ip+f*16);
      float4 x0=xp[0],x1=xp[1],x2=xp[2],x3=xp[3];
      float w0v=wp[(f<<5)+g],w1v=wp[1024+(f<<5)+g],w2v=wp[2048+(f<<5)+g],w3v=wp[3072+(f<<5)+g];
      A[0]=fmaf(x0.x,w0v,A[0]);  A[1]=fmaf(x0.y,w1v,A[1]);  A[2]=fmaf(x0.z,w1v,A[2]);  A[3]=fmaf(x0.w,w1v,A[3]);
      A[4]=fmaf(x1.x,w2v,A[4]);  A[5]=fmaf(x1.y,w2v,A[5]);  A[6]=fmaf(x1.z,w2v,A[6]);  A[7]=fmaf(x1.w,w2v,A[7]);
      A[8]=fmaf(x2.x,w2v,A[8]);  A[9]=fmaf(x2.y,w3v,A[9]);  A[10]=fmaf(x2.z,w3v,A[10]);A[11]=fmaf(x2.w,w3v,A[11]);
      A[12]=fmaf(x3.x,w3v,A[12]);A[13]=fmaf(x3.y,w3v,A[13]);A[14]=fmaf(x3.z,w3v,A[14]);A[15]=fmaf(x3.w,w3v,A[15]);
    }
    float B2[16];
    #pragma unroll
    for(int c=0;c<16;c++) B2[c]=0.f;
    tpn_paths<0>(A,A,B2);
    float B3_0=tpn_scalar(B2,A);
    int zz=z[n];
    float wa=pb1[zz*96+g], wb=pb1[zz*96+32+g], wc=pb1[zz*96+64+g];
    sh[n0*32+g]=wa*A[0]+wb*B2[0]+wc*B3_0;
  }
  __syncthreads();
  if(act){
    float a=0.f;
    #pragma unroll 8
    for(int f=0;f<32;f++) a=fmaf(sh[n0*32+f], pblin1[(f<<5)+g], a);
    sh2[n0*32+g]=a+resid[(size_t)n*32+g];
  }
  __syncthreads();
  if(g==0){
    float val=0.f;
    if(act){
      float e1=0.f;
      #pragma unroll
      for(int j=0;j<16;j++){
        float a=0.f;
        #pragma unroll
        for(int f=0;f<32;f++) a=fmaf(sh2[n0*32+f],ro1a[f*16+j],a);
        float s=a/(1.f+__expf(-a));
        e1=fmaf(s,ro1b[j],e1);
      }
      val=-1.5f+2.0f*(e0a[n]+e1)-10.0f;
    }
    red[n0]=val;
  }
  __syncthreads();
  if(tid==0){
    float s=0.f;
    #pragma unroll
    for(int i=0;i<8;i++) s+=red[i];
    atomicAdd(out,s);
  }
}

// ---------------- host orchestration ----------------
extern "C" void kernel_launch(void* const* d_in, const int* in_sizes, int n_in,
                              void* d_out, int out_size, void* d_ws, size_t ws_size,
                              hipStream_t stream)
{
  const float* vec   =(const float*)d_in[0];
  const int*   zarr  =(const int*)  d_in[1];
  const int*   snd   =(const int*)  d_in[2];
  const int*   rcv   =(const int*)  d_in[3];
  const float* embed =(const float*)d_in[4];
  const float* r0w0  =(const float*)d_in[5];
  const float* r0w1  =(const float*)d_in[6];
  const float* r0w2  =(const float*)d_in[7];
  const float* up0   =(const float*)d_in[8];
  const float* post0 =(const float*)d_in[9];
  const float* pb0   =(const float*)d_in[10];
  const float* pblin0=(const float*)d_in[11];
  const float* r1w0  =(const float*)d_in[12];
  const float* r1w1  =(const float*)d_in[13];
  const float* r1w2  =(const float*)d_in[14];
  const float* up1   =(const float*)d_in[15];
  const float* post1 =(const float*)d_in[16];
  const float* pb1   =(const float*)d_in[17];
  const float* pblin1=(const float*)d_in[18];
  const float* sel0  =(const float*)d_in[19];
  const float* ro0   =(const float*)d_in[20];
  const float* res1  =(const float*)d_in[21];
  const float* ro1a  =(const float*)d_in[22];
  const float* ro1b  =(const float*)d_in[23];

  const int E = in_sizes[0]/3;
  const int N = in_sizes[1];

  char* ws=(char*)d_ws;
  size_t o=0;
  auto alloc=[&](size_t bytes)->char*{
    char* p=ws+o;
    o=(o+bytes+255)&~(size_t)255;
    return p;
  };
  int*   deg  =(int*)  alloc((size_t)N*4);
  int*   rowp =(int*)  alloc((size_t)(N+1)*4);
  int*   cur  =(int*)  alloc((size_t)N*4);
  int*   eid  =(int*)  alloc((size_t)E*4);
  int*   snd_s=(int*)  alloc((size_t)E*4);
  int*   rcv_s=(int*)  alloc((size_t)E*4);
  float* Yb   =(float*)alloc((size_t)E*16*4);
  float* radb =(float*)alloc((size_t)E*8*4);
  unsigned short* w2t0=(unsigned short*)alloc((size_t)1088*64*2);
  unsigned short* w2t1=(unsigned short*)alloc((size_t)1088*64*2);
  unsigned short* hl16=(unsigned short*)alloc((size_t)N*512*2);
  float* combw=(float*)alloc((size_t)10*4096*4);
  float* bufB =(float*)alloc((size_t)N*512*4);
  float* bufC =(float*)alloc((size_t)N*512*4);
  float* e0b  =(float*)alloc((size_t)N*4);
  float* residb=(float*)alloc((size_t)N*32*4);

  dim3 tb(256);
  dim3 nblk((unsigned)((N*32+255)/256));
  dim3 n8blk((unsigned)((N+7)/8));
  dim3 eblk((unsigned)((E+255)/256));
  dim3 e16blk((unsigned)((E+15)/16));

  // CSR build (receiver-sorted edge order)
  hipMemsetAsync(deg,0,(size_t)N*4,stream);
  k_count<<<eblk,tb,0,stream>>>(rcv,deg,E);
  k_scan<<<dim3(1),dim3(1024),0,stream>>>(deg,rowp,cur,N);
  k_fill<<<eblk,tb,0,stream>>>(rcv,cur,eid,E);

  k_edge_setup<<<eblk,tb,0,stream>>>(vec,snd,rcv,eid,Yb,radb,snd_s,rcv_s,E);
  k_prep<<<dim3((2*1088*64+10*4096+255)/256),tb,0,stream>>>(r0w2,r1w2,w2t0,w2t1,post0,sel0,combw);
  k_embed16<<<nblk,tb,0,stream>>>(embed,up0,zarr,hl16,N);

  auto run_edges=[&](bool l0, const unsigned short* hlin, const float* w0,
                     const float* w1, const unsigned short* w2t, float* agg){
    hipMemsetAsync(agg,0,(size_t)N*512*4,stream);
    if(l0) k_tp_fused<true ><<<e16blk,tb,0,stream>>>(hlin,Yb,radb,w0,w1,w2t,snd_s,rcv_s,agg,E);
    else   k_tp_fused<false><<<e16blk,tb,0,stream>>>(hlin,Yb,radb,w0,w1,w2t,snd_s,rcv_s,agg,E);
  };

  // ---- layer 0 ----
  run_edges(true,hl16,r0w0,r0w1,w2t0,bufB);
  k_node0<<<n8blk,tb,0,stream>>>(bufB,combw,pb0,pblin0,ro0,res1,up1,zarr,e0b,residb,hl16,N);

  // ---- layer 1 ----
  run_edges(false,hl16,r1w0,r1w1,w2t1,bufC);
  hipMemsetAsync(d_out,0,4,stream);
  k_node1<<<n8blk,tb,0,stream>>>(bufC,post1,pb1,pblin1,zarr,residb,e0b,ro1a,ro1b,(float*)d_out,N);
}

// Round 12
// 607.669 us; speedup vs baseline: 2.1838x; 2.1838x over previous
//
#include <hip/hip_runtime.h>
#include <math.h>

// ---------------- static config ----------------
#define NF 32
#define NPATHS 34

typedef __attribute__((ext_vector_type(8))) short bf16x8;
typedef __attribute__((ext_vector_type(4))) float f32x4;
typedef __attribute__((ext_vector_type(2))) float f32x2;

__device__ __forceinline__ unsigned short f2bf(float v){
  unsigned u = __float_as_uint(v);
  u += 0x7fffu + ((u>>16)&1u);
  return (unsigned short)(u>>16);
}
__device__ __forceinline__ float bf2f(unsigned short h){
  return __uint_as_float(((unsigned)h)<<16);
}

struct PathTab { int l1[NPATHS]; int l2[NPATHS]; int l3[NPATHS]; };
constexpr PathTab mkpaths(){
  PathTab t{}; int n=0;
  for(int a=0;a<=3;a++)for(int b=0;b<=3;b++)for(int c=0;c<=3;c++){
    int lo = a>b ? a-b : b-a;
    if(c>=lo && c<=a+b){ t.l1[n]=a; t.l2[n]=b; t.l3[n]=c; n++; }
  }
  return t;
}
constexpr PathTab PT = mkpaths();

// ---------------- compile-time Wigner-3j (exact replica of reference math) ----------------
struct FactT { double v[22]; };
constexpr FactT mkfactT(){ FactT f{}; f.v[0]=1.0; for(int i=1;i<22;i++) f.v[i]=f.v[i-1]*(double)i; return f; }
constexpr FactT FT = mkfactT();
constexpr double cfact(int n){ return FT.v[n]; }

constexpr double csqrt(double x){
  if(x<=0.0) return 0.0;
  double g = x<1.0 ? 1.0 : x;
  for(int i=0;i<40;i++) g=0.5*(g+x/g);
  return g;
}

constexpr double su2cg(int j1,int j2,int j3,int m1,int m2){
  int m3=m1+m2;
  if(m3<-j3||m3>j3) return 0.0;
  double pref = (double)(2*j3+1)*cfact(j3+j1-j2)*cfact(j3-j1+j2)*cfact(j1+j2-j3)/cfact(j1+j2+j3+1);
  pref *= cfact(j3+m3)*cfact(j3-m3)*cfact(j1-m1)*cfact(j1+m1)*cfact(j2-m2)*cfact(j2+m2);
  pref = csqrt(pref);
  int k0=0; if(j2-j3-m1>k0)k0=j2-j3-m1; if(j1-j3+m2>k0)k0=j1-j3+m2;
  int k1=j1+j2-j3; if(j1-m1<k1)k1=j1-m1; if(j2+m2<k1)k1=j2+m2;
  double s=0.0;
  for(int k=k0;k<=k1;k++){
    double d = cfact(k)*cfact(j1+j2-j3-k)*cfact(j1-m1-k)*cfact(j2+m2-k)*cfact(j3-j2+m1+k)*cfact(j3-j1-m2+k);
    s += (k&1)? -1.0/d : 1.0/d;
  }
  return pref*s;
}

struct ccd { double x, y; };
constexpr ccd cqval(int l,int r,int col){
  const double is2 = 0.70710678118654752440;
  double re=0.0, im=0.0;
  if (r<l){ if (col==2*l-r) re=is2; else if (col==r) im=-is2; }
  else if (r==l){ if (col==l) re=1.0; }
  else { double s = ((r-l)&1)? -1.0:1.0;
         if (col==r) re=s*is2; else if (col==2*l-r) im=s*is2; }
  ccd v{re,im};
  switch(l&3){           // multiply by (-i)^l
    case 1: return ccd{ v.y, -v.x };
    case 2: return ccd{-v.x, -v.y };
    case 3: return ccd{-v.y,  v.x };
    default: return v;
  }
}

constexpr double w3entry(int l1,int l2,int l3,int i,int j,int k){
  double re=0.0;
  for(int a=0;a<2*l1+1;a++){
    ccd qa=cqval(l1,a,i); if(qa.x==0.0&&qa.y==0.0) continue;
    for(int b=0;b<2*l2+1;b++){
      ccd qb=cqval(l2,b,j); if(qb.x==0.0&&qb.y==0.0) continue;
      int m1=a-l1, m2=b-l2, m3=m1+m2;
      if(m3<-l3||m3>l3) continue;
      int c=m3+l3;
      double cg=su2cg(l1,l2,l3,m1,m2); if(cg==0.0) continue;
      ccd qc=cqval(l3,c,k); qc.y=-qc.y;   // conj
      if(qc.x==0.0&&qc.y==0.0) continue;
      ccd ab{qa.x*qb.x-qa.y*qb.y, qa.x*qb.y+qa.y*qb.x};
      re += cg*(ab.x*qc.x - ab.y*qc.y);
    }
  }
  return re;
}

template<int L1,int L2,int L3> struct W3Arr { float v[(2*L1+1)*(2*L2+1)*(2*L3+1)]; };
template<int L1,int L2,int L3> constexpr W3Arr<L1,L2,L3> mkW3(double scale){
  W3Arr<L1,L2,L3> r{};
  for(int i=0;i<2*L1+1;i++)
    for(int j=0;j<2*L2+1;j++)
      for(int k=0;k<2*L3+1;k++)
        r.v[(i*(2*L2+1)+j)*(2*L3+1)+k] = (float)(w3entry(L1,L2,L3,i,j,k)*scale);
  return r;
}
template<int L1,int L2,int L3> constexpr W3Arr<L1,L2,L3> W3V = mkW3<L1,L2,L3>(1.0);
template<int L1,int L2,int L3> constexpr W3Arr<L1,L2,L3> W3N = mkW3<L1,L2,L3>(1.0/csqrt(2.0*L3+1.0));

// SH recursion scales (replica of reference _sh_scales, float64 like numpy)
struct SCt { double sc2, sc3; };
constexpr SCt mksc(){
  double v0=0.2,v1=-0.6,v2=0.7;
  double nv=csqrt(v0*v0+v1*v1+v2*v2);
  double s3=csqrt(3.0);
  double y1[3]={s3*v0/nv, s3*v1/nv, s3*v2/nv};
  double t2[5]={0,0,0,0,0}; double n2=0.0;
  for(int c=0;c<5;c++){
    double s=0.0;
    for(int a=0;a<3;a++)for(int b=0;b<3;b++) s += w3entry(1,1,2,a,b,c)*y1[a]*y1[b];
    t2[c]=s; n2+=s*s;
  }
  double sc2=csqrt(5.0)/csqrt(n2);
  double y2[5]={sc2*t2[0],sc2*t2[1],sc2*t2[2],sc2*t2[3],sc2*t2[4]};
  double n3=0.0;
  for(int c=0;c<7;c++){
    double s=0.0;
    for(int a=0;a<5;a++)for(int b=0;b<3;b++) s += w3entry(2,1,3,a,b,c)*y2[a]*y1[b];
    n3+=s*s;
  }
  double sc3=csqrt(7.0)/csqrt(n3);
  return SCt{sc2,sc3};
}
constexpr SCt SCV = mksc();

// ---------------- scalar template-unrolled TP with literal W3J (node kernels + SH) ----------------
template<bool NORM,int l1,int l2,int l3,int A,int B,int C>
__device__ __forceinline__ void w3term(const float* __restrict__ x, const float* __restrict__ y,
                                       float rv, float* __restrict__ acc){
  constexpr float w = NORM ? W3N<l1,l2,l3>.v[(A*(2*l2+1)+B)*(2*l3+1)+C]
                           : W3V<l1,l2,l3>.v[(A*(2*l2+1)+B)*(2*l3+1)+C];
  if constexpr (w!=0.0f)
    acc[l3*l3+C] = fmaf(w, x[l1*l1+A]*y[l2*l2+B]*rv, acc[l3*l3+C]);
}
template<bool NORM,int l1,int l2,int l3,int A,int B,int C>
__device__ __forceinline__ void w3loopC(const float* x,const float* y,float rv,float* acc){
  if constexpr (C<2*l3+1){
    w3term<NORM,l1,l2,l3,A,B,C>(x,y,rv,acc);
    w3loopC<NORM,l1,l2,l3,A,B,C+1>(x,y,rv,acc);
  }
}
template<bool NORM,int l1,int l2,int l3,int A,int B>
__device__ __forceinline__ void w3loopB(const float* x,const float* y,float rv,float* acc){
  if constexpr (B<2*l2+1){
    w3loopC<NORM,l1,l2,l3,A,B,0>(x,y,rv,acc);
    w3loopB<NORM,l1,l2,l3,A,B+1>(x,y,rv,acc);
  }
}
template<bool NORM,int l1,int l2,int l3,int A>
__device__ __forceinline__ void w3loopA(const float* x,const float* y,float rv,float* acc){
  if constexpr (A<2*l1+1){
    w3loopB<NORM,l1,l2,l3,A,0>(x,y,rv,acc);
    w3loopA<NORM,l1,l2,l3,A+1>(x,y,rv,acc);
  }
}

template<int P>
__device__ __forceinline__ void tpn_paths(const float* x,const float* y,float* o){
  if constexpr (P<NPATHS){
    constexpr int l1=PT.l1[P], l2=PT.l2[P], l3=PT.l3[P];
    w3loopA<true,l1,l2,l3,0>(x,y,1.0f,o);
    tpn_paths<P+1>(x,y,o);
  }
}

// scalar-only node TP: l3=0 paths (l,l,0) only
__device__ __forceinline__ float tpn_scalar(const float* x,const float* y){
  float o[1]={0.f};
  w3loopA<true,0,0,0,0>(x,y,1.0f,o);
  w3loopA<true,1,1,0,0>(x,y,1.0f,o);
  w3loopA<true,2,2,0,0>(x,y,1.0f,o);
  w3loopA<true,3,3,0,0>(x,y,1.0f,o);
  return o[0];
}

// ---------------- packed-pair (two edges per thread, f32x2 -> v_pk_fma_f32) TP ----------------
template<int l1,int l2,int l3,int A,int B>
constexpr bool anyNZ(){
  for(int c=0;c<2*l3+1;c++)
    if(W3V<l1,l2,l3>.v[(A*(2*l2+1)+B)*(2*l3+1)+c]!=0.0f) return true;
  return false;
}
template<int l1,int l2,int l3,int A,int B,int C>
__device__ __forceinline__ void w3C2(const f32x2 p, f32x2* __restrict__ S){
  constexpr float w = W3V<l1,l2,l3>.v[(A*(2*l2+1)+B)*(2*l3+1)+C];
  if constexpr (w!=0.0f) S[C] = p*w + S[C];
  if constexpr (C+1<2*l3+1) w3C2<l1,l2,l3,A,B,C+1>(p,S);
}
template<int l1,int l2,int l3,int A,int B>
__device__ __forceinline__ void w3B2(const f32x2* __restrict__ x,const f32x2* __restrict__ y,
                                     f32x2* __restrict__ S){
  if constexpr (anyNZ<l1,l2,l3,A,B>()){
    f32x2 p = x[l1*l1+A]*y[l2*l2+B];
    w3C2<l1,l2,l3,A,B,0>(p,S);
  }
  if constexpr (B+1<2*l2+1) w3B2<l1,l2,l3,A,B+1>(x,y,S);
}
template<int l1,int l2,int l3,int A>
__device__ __forceinline__ void w3A2(const f32x2* __restrict__ x,const f32x2* __restrict__ y,
                                     f32x2* __restrict__ S){
  w3B2<l1,l2,l3,A,0>(x,y,S);
  if constexpr (A+1<2*l1+1) w3A2<l1,l2,l3,A+1>(x,y,S);
}
// R25 layout: rws element (P,f,le) at u16 index (P*32+f)*34 + le, le in [0,32).
// rp = rws + f*34 + leA; path P -> rp[P*1088] (edge A) and rp[P*1088+16] (edge B = leA+16).
// f-lane stride 68B = 17 dwords, gcd(17,32)=1 -> all 32 banks.
template<bool L0,int P>
__device__ __forceinline__ void tp2(const f32x2* __restrict__ x,const f32x2* __restrict__ y,
                                    const unsigned short* __restrict__ rp,
                                    f32x2* __restrict__ acc){
  if constexpr (P<NPATHS){
    constexpr int l1=PT.l1[P], l2=PT.l2[P], l3=PT.l3[P];
    if constexpr (!(L0 && l1!=0)){
      f32x2 S[2*l3+1];
      #pragma unroll
      for(int c=0;c<2*l3+1;c++) S[c]=(f32x2){0.f,0.f};
      w3A2<l1,l2,l3,0>(x,y,S);
      f32x2 rv = { bf2f(rp[P*1088]), bf2f(rp[P*1088+16]) };
      #pragma unroll
      for(int c=0;c<2*l3+1;c++) acc[l3*l3+c] = rv*S[c] + acc[l3*l3+c];
    }
    tp2<L0,P+1>(x,y,rp,acc);
  }
}

// ---------------- CSR build: degree count, scan, fill ----------------
__global__ __launch_bounds__(256) void k_count(
    const int* __restrict__ rcv, int* __restrict__ deg, int E)
{
  int e=blockIdx.x*256+threadIdx.x;
  if(e>=E) return;
  atomicAdd(&deg[rcv[e]],1);
}

#define SCAN_PER 32
__global__ __launch_bounds__(1024) void k_scan(
    const int* __restrict__ deg, int* __restrict__ row,
    int* __restrict__ cur, int N)
{
  __shared__ int part[1024];
  int t=threadIdx.x;
  int per=(N+1023)/1024; if(per>SCAN_PER) per=SCAN_PER;
  int base=t*per;
  int loc[SCAN_PER];
  int s=0;
  for(int i=0;i<per;i++){ int idx=base+i; int v=(idx<N)? deg[idx]:0; loc[i]=s; s+=v; }
  part[t]=s;
  __syncthreads();
  for(int off=1;off<1024;off<<=1){
    int v=(t>=off)? part[t-off]:0;
    __syncthreads();
    part[t]+=v;
    __syncthreads();
  }
  int ex=(t==0)?0:part[t-1];
  for(int i=0;i<per;i++){
    int idx=base+i;
    if(idx<N){ int r=ex+loc[i]; row[idx]=r; cur[idx]=r; }
  }
  if(t==1023) row[N]=part[1023];
}

__global__ __launch_bounds__(256) void k_fill(
    const int* __restrict__ rcv, int* __restrict__ cur,
    int* __restrict__ eid, int E)
{
  int e=blockIdx.x*256+threadIdx.x;
  if(e>=E) return;
  int pos=atomicAdd(&cur[rcv[e]],1);
  eid[pos]=e;
}

// ---------------- per-edge geometry (receiver-sorted order): SH + radial basis ----------------
__global__ __launch_bounds__(256) void k_edge_setup(
    const float* __restrict__ vec, const int* __restrict__ snd,
    const int* __restrict__ rcv, const int* __restrict__ eid,
    float* __restrict__ Y, float* __restrict__ rad,
    int* __restrict__ snd_s, int* __restrict__ rcv_s, int E)
{
  int j = blockIdx.x*256+threadIdx.x;
  if (j>=E) return;
  int e = eid[j];
  snd_s[j]=snd[e];
  rcv_s[j]=rcv[e];
  float vx=vec[3*e], vy=vec[3*e+1], vz=vec[3*e+2];
  float r=sqrtf(vx*vx+vy*vy+vz*vz);
  float inv=1.0f/fmaxf(r,1e-9f);
  float y[16];
  y[0]=1.0f;
  const float s3=1.7320508075688772f;
  y[1]=s3*vx*inv; y[2]=s3*vy*inv; y[3]=s3*vz*inv;
  constexpr float sc2=(float)SCV.sc2, sc3=(float)SCV.sc3;
  {
    float t[16];
    #pragma unroll
    for(int c=0;c<16;c++) t[c]=0.f;
    w3loopA<false,1,1,2,0>(y,y,1.0f,t);
    #pragma unroll
    for(int c=0;c<5;c++) y[4+c]=sc2*t[4+c];
    w3loopA<false,2,1,3,0>(y,y,1.0f,t);
    #pragma unroll
    for(int c=0;c<7;c++) y[9+c]=sc3*t[9+c];
  }
  float4* Yp=(float4*)(Y+(size_t)j*16);
  Yp[0]=make_float4(y[0],y[1],y[2],y[3]);
  Yp[1]=make_float4(y[4],y[5],y[6],y[7]);
  Yp[2]=make_float4(y[8],y[9],y[10],y[11]);
  Yp[3]=make_float4(y[12],y[13],y[14],y[15]);
  float x = r*0.2f;
  float env=0.f;
  if (x<1.0f){
    float x2=x*x; float x4=x2*x2; float x5=x4*x;
    env = 1.0f - 21.0f*x5 + 35.0f*x5*x - 15.0f*x5*x2;
  }
  const float cb = 0.632455532033675866f; // sqrt(2/5)
  float base = inv*env*cb;
  #pragma unroll
  for(int n=1;n<=8;n++)
    rad[(size_t)j*8 + n-1] = base*sinf(3.14159265358979323846f * x * (float)n);
}

// ---------------- layer-0 hlin directly from scalar embedding (bf16) ----------------
__global__ __launch_bounds__(256) void k_embed16(
    const float* __restrict__ embed, const float* __restrict__ up0,
    const int* __restrict__ z, unsigned short* __restrict__ hl16, int N)
{
  int t=blockIdx.x*256+threadIdx.x;
  int n=t>>5, g=t&31;
  if(n>=N) return;
  const float* ep=embed+z[n]*32;
  float a=0.f;
  #pragma unroll 8
  for(int f=0;f<32;f++) a=fmaf(ep[f],up0[(f<<5)+g],a);
  bf16x8 o0={(short)f2bf(a),0,0,0,0,0,0,0};
  bf16x8 o1={0,0,0,0,0,0,0,0};
  bf16x8* op=(bf16x8*)(hl16+(size_t)n*512+g*16);
  op[0]=o0; op[1]=o1;
}

// ---------------- radial MLP hidden layers (bf16 output) ----------------
__global__ __launch_bounds__(256) void k_radial(
    const float* __restrict__ rad, const float* __restrict__ w0,
    const float* __restrict__ w1, unsigned short* __restrict__ hid, int E)
{
  __shared__ float w0s[8*64];
  __shared__ float w1s[64*64];
  int tid=threadIdx.x;
  for(int i=tid;i<512;i+=256) w0s[i]=w0[i];
  for(int i=tid;i<4096;i+=256) w1s[i]=w1[i];
  __syncthreads();
  int e=blockIdx.x*256+tid;
  if(e>=E) return;
  const float4* rp=(const float4*)(rad+(size_t)e*8);
  float4 ra=rp[0], rb=rp[1];
  float rv[8]={ra.x,ra.y,ra.z,ra.w,rb.x,rb.y,rb.z,rb.w};
  float h1[64];
  #pragma unroll 8
  for(int j=0;j<64;j++){
    float a=0.f;
    #pragma unroll
    for(int i=0;i<8;i++) a=fmaf(rv[i],w0s[i*64+j],a);
    h1[j]=a/(1.f+__expf(-a));
  }
  unsigned short* hp = hid+(size_t)e*64;
  #pragma unroll 4
  for(int j=0;j<64;j++){
    float a=0.f;
    #pragma unroll
    for(int i=0;i<64;i++) a=fmaf(h1[i],w1s[i*64+j],a);
    hp[j]=f2bf(a/(1.f+__expf(-a)));
  }
}

// ---------------- weight prep: cast+transpose both w2, and comb = post0@sel0 ----------------
__global__ __launch_bounds__(256) void k_prep(
    const float* __restrict__ w2a, const float* __restrict__ w2b,
    unsigned short* __restrict__ ta, unsigned short* __restrict__ tb,
    const float* __restrict__ post0, const float* __restrict__ sel0,
    float* __restrict__ comb)
{
  int t=blockIdx.x*256+threadIdx.x;
  const int C2=2*1088*64;
  if(t<C2){
    const float* src = (t<1088*64)? w2a : w2b;
    unsigned short* dst = (t<1088*64)? ta : tb;
    int u = (t<1088*64)? t : t-1088*64;
    int c=u>>6, k=u&63;
    dst[(size_t)c*64+k]=f2bf(src[(size_t)k*1088+c]);
  } else {
    int u=t-C2;
    if(u<10*4096){
      int z=u>>12, r=u&4095;
      int l=r>>10, e=(r>>5)&31, g=r&31;
      const float* pp=post0+l*1024+e*32;
      const float* sp=sel0+(size_t)z*4096+l*1024;
      float a=0.f;
      #pragma unroll 8
      for(int f=0;f<32;f++) a=fmaf(pp[f], sp[f*32+g], a);
      comb[(size_t)z*4096 + l*1024 + e*32 + g]=a;
    }
  }
}

// ---------------- FUSED: MFMA rw-GEMM (LDS) + packed-pair edge TP + in-block segment reduce ----------------
// R23 verified best (583.7). R24 (radial fusion) regressed 2.3x — reverted (latency-chain
// poisoning, not bubble-filling). R25: 32-edge blocks. Each 16-wide w2t column tile is
// loaded ONCE and feeds TWO MFMAs (edges 0-15 / 16-31) -> w2t L2 traffic and per-edge
// phase-1 load cost halve (was 1.1GB L2/dispatch); block count and phase-3 atomics/edge
// also halve. LDS: rws [P][f][le:32] stride-34 u16 (17-dword f-stride, gcd(17,32)=1 ->
// full banks) union lmsg 32x(32x17) f32 = 74KB -> 2 blocks/CU.
// Phase 2: two pk-pairs per thread (pairs (q+8p, q+8p+16)), statically unrolled.
template<bool L0>
__global__ __launch_bounds__(256) void k_tp_fused(
    const unsigned short* __restrict__ hlin, const float* __restrict__ Y,
    const unsigned short* __restrict__ hid, const unsigned short* __restrict__ w2t,
    const int* __restrict__ snd_s, const int* __restrict__ rcv_s,
    float* __restrict__ agg, int ecnt)
{
  constexpr int NT  = L0 ? 8 : 68;      // 16-wide col tiles of the rw GEMM
  constexpr int PD  = L0 ? 4 : 34;      // P dim of rws
  constexpr int RWSU = PD*32*34;        // u16 in the rw strip (le:32, stride 34)
  constexpr int LMU  = 32*32*17*2;      // u16 backing 32x(32x17) f32 lmsg
  constexpr int LDSU = RWSU > LMU ? RWSU : LMU;
  __shared__ unsigned short rws[LDSU] __attribute__((aligned(16)));
  __shared__ int r32v[32];
  int tid=threadIdx.x;
  int lane=tid&63, wave=tid>>6;
  int m16=lane&15, quad=lane>>4;
  int el0=blockIdx.x*32;
  int f=tid&31;
  int q=tid>>5;                          // 0..7
  if(tid<32) r32v[tid] = (el0+tid<ecnt) ? rcv_s[el0+tid] : -1;
  // ---- phase 1: rw GEMM for 32 edges; each B tile feeds 2 MFMAs ----
  {
    const unsigned short* Ab = hid + (size_t)el0*64;
    bf16x8 a0g0 = *(const bf16x8*)(Ab + m16*64 + quad*8);
    bf16x8 a1g0 = *(const bf16x8*)(Ab + m16*64 + 32 + quad*8);
    bf16x8 a0g1 = *(const bf16x8*)(Ab + (16+m16)*64 + quad*8);
    bf16x8 a1g1 = *(const bf16x8*)(Ab + (16+m16)*64 + 32 + quad*8);
    #pragma unroll 2
    for(int nt=wave; nt<NT; nt+=4){
      int col = nt*16 + m16;
      bf16x8 b0 = *(const bf16x8*)(w2t + (size_t)col*64 + quad*8);
      bf16x8 b1 = *(const bf16x8*)(w2t + (size_t)col*64 + 32 + quad*8);
      f32x4 acc0 = (f32x4){0.f,0.f,0.f,0.f};
      f32x4 acc1 = (f32x4){0.f,0.f,0.f,0.f};
      acc0 = __builtin_amdgcn_mfma_f32_16x16x32_bf16(a0g0,b0,acc0,0,0,0);
      acc0 = __builtin_amdgcn_mfma_f32_16x16x32_bf16(a1g0,b1,acc0,0,0,0);
      acc1 = __builtin_amdgcn_mfma_f32_16x16x32_bf16(a0g1,b0,acc1,0,0,0);
      acc1 = __builtin_amdgcn_mfma_f32_16x16x32_bf16(a1g1,b1,acc1,0,0,0);
      int fc = col&31, P = col>>5;
      unsigned* wp = (unsigned*)(rws + (size_t)(P*32+fc)*34);
      unsigned w0 = (unsigned)f2bf(acc0[0]) | ((unsigned)f2bf(acc0[1])<<16);
      unsigned w1 = (unsigned)f2bf(acc0[2]) | ((unsigned)f2bf(acc0[3])<<16);
      wp[quad*2]   = w0;
      wp[quad*2+1] = w1;
      unsigned w2 = (unsigned)f2bf(acc1[0]) | ((unsigned)f2bf(acc1[1])<<16);
      unsigned w3 = (unsigned)f2bf(acc1[2]) | ((unsigned)f2bf(acc1[3])<<16);
      wp[8+quad*2]   = w2;
      wp[8+quad*2+1] = w3;
    }
  }
  __syncthreads();
  // ---- phase 2: two pk-pairs per thread: (q+8p, q+8p+16), p=0,1 ----
  f32x2 accP0[16], accP1[16];
  bool okA0, okB0, okA1, okB1;
  #pragma unroll
  for(int pp=0;pp<2;pp++){
    int leA = q + pp*8, leB = leA + 16;
    int elA = el0 + leA, elB = el0 + leB;
    bool okA = elA<ecnt, okB = elB<ecnt;
    if(pp==0){ okA0=okA; okB0=okB; } else { okA1=okA; okB1=okB; }
    int sA = okA ? snd_s[elA] : 0;
    int sB = okB ? snd_s[elB] : 0;
    size_t jA = okA ? (size_t)elA : 0;
    size_t jB = okB ? (size_t)elB : 0;
    f32x2 hs[16];
    if constexpr (L0){
      hs[0] = (f32x2){ bf2f(hlin[(size_t)sA*512 + f*16]),
                       bf2f(hlin[(size_t)sB*512 + f*16]) };
    } else {
      const bf16x8* hA = (const bf16x8*)(hlin + (size_t)sA*512 + f*16);
      const bf16x8* hB = (const bf16x8*)(hlin + (size_t)sB*512 + f*16);
      bf16x8 ha0=hA[0], ha1=hA[1], hb0=hB[0], hb1=hB[1];
      #pragma unroll
      for(int c=0;c<8;c++){
        hs[c]   = (f32x2){ bf2f((unsigned short)ha0[c]), bf2f((unsigned short)hb0[c]) };
        hs[8+c] = (f32x2){ bf2f((unsigned short)ha1[c]), bf2f((unsigned short)hb1[c]) };
      }
    }
    f32x2 yv[16];
    {
      const float4* yA=(const float4*)(Y+jA*16);
      const float4* yB=(const float4*)(Y+jB*16);
      float4 a0=yA[0],a1=yA[1],a2=yA[2],a3=yA[3];
      float4 b0=yB[0],b1=yB[1],b2=yB[2],b3=yB[3];
      yv[0]=(f32x2){a0.x,b0.x}; yv[1]=(f32x2){a0.y,b0.y}; yv[2]=(f32x2){a0.z,b0.z}; yv[3]=(f32x2){a0.w,b0.w};
      yv[4]=(f32x2){a1.x,b1.x}; yv[5]=(f32x2){a1.y,b1.y}; yv[6]=(f32x2){a1.z,b1.z}; yv[7]=(f32x2){a1.w,b1.w};
      yv[8]=(f32x2){a2.x,b2.x}; yv[9]=(f32x2){a2.y,b2.y}; yv[10]=(f32x2){a2.z,b2.z}; yv[11]=(f32x2){a2.w,b2.w};
      yv[12]=(f32x2){a3.x,b3.x}; yv[13]=(f32x2){a3.y,b3.y}; yv[14]=(f32x2){a3.z,b3.z}; yv[15]=(f32x2){a3.w,b3.w};
    }
    const unsigned short* rp = rws + f*34 + leA;
    f32x2* acc = (pp==0)? accP0 : accP1;
    #pragma unroll
    for(int c=0;c<16;c++) acc[c]=(f32x2){0.f,0.f};
    tp2<L0,0>(hs,yv,rp,acc);
  }
  // ---- phase 3: stage f32 messages in LDS (stride-17 rows), segment-reduce, atomicAdd ----
  __syncthreads();                       // all tp2 LDS reads done; safe to overwrite
  float* lm = (float*)rws;               // lmsg[(le*32+f)*17 + c]
  if(okA0){
    #pragma unroll
    for(int c=0;c<16;c++) lm[((q)*32+f)*17+c] = accP0[c].x*0.0625f;
  }
  if(okB0){
    #pragma unroll
    for(int c=0;c<16;c++) lm[((q+16)*32+f)*17+c] = accP0[c].y*0.0625f;
  }
  if(okA1){
    #pragma unroll
    for(int c=0;c<16;c++) lm[((q+8)*32+f)*17+c] = accP1[c].x*0.0625f;
  }
  if(okB1){
    #pragma unroll
    for(int c=0;c<16;c++) lm[((q+24)*32+f)*17+c] = accP1[c].y*0.0625f;
  }
  __syncthreads();
  #pragma unroll
  for(int s=tid; s<512; s+=256){
    float run=0.f; int cur=-1;
    #pragma unroll
    for(int le=0; le<32; le++){
      int rr = r32v[le];
      if(rr != cur){
        if(cur >= 0) atomicAdd(agg + (size_t)cur*512 + s, run);
        run = 0.f; cur = rr;
      }
      if(rr >= 0) run += lm[(le*32+(s>>4))*17 + (s&15)];
    }
    if(cur >= 0) atomicAdd(agg + (size_t)cur*512 + s, run);
  }
}

// ---------------- fused layer-0 node chain: lin(comb)+tp_node(pb0)+pblin0+readout+up1->hl16 ----------------
__global__ __launch_bounds__(256) void k_node0(
    const float* __restrict__ agg, const float* __restrict__ combw,
    const float* __restrict__ pb0, const float* __restrict__ pblin0,
    const float* __restrict__ ro0, const float* __restrict__ res1,
    const float* __restrict__ up1, const int* __restrict__ z,
    float* __restrict__ e0, float* __restrict__ resid,
    unsigned short* __restrict__ hl16, int N)
{
  __shared__ float sh1[8*512] __attribute__((aligned(16)));
  __shared__ float sh2[8*512] __attribute__((aligned(16)));
  int tid=threadIdx.x;
  int n0=tid>>5, g=tid&31;
  int n=blockIdx.x*8+n0;
  bool act=(n<N);
  int zz = act? z[n] : 0;
  if(act){
    const float* wp = combw + (size_t)zz*4096;
    const float* ip = agg + (size_t)n*512;
    float A[16];
    #pragma unroll
    for(int c=0;c<16;c++) A[c]=0.f;
    #pragma unroll 8
    for(int f=0;f<NF;f++){
      const float4* xp=(const float4*)(ip+f*16);
      float4 x0=xp[0],x1=xp[1],x2=xp[2],x3=xp[3];
      float w0v=wp[(f<<5)+g],w1v=wp[1024+(f<<5)+g],w2v=wp[2048+(f<<5)+g],w3v=wp[3072+(f<<5)+g];
      A[0]=fmaf(x0.x,w0v,A[0]);  A[1]=fmaf(x0.y,w1v,A[1]);  A[2]=fmaf(x0.z,w1v,A[2]);  A[3]=fmaf(x0.w,w1v,A[3]);
      A[4]=fmaf(x1.x,w2v,A[4]);  A[5]=fmaf(x1.y,w2v,A[5]);  A[6]=fmaf(x1.z,w2v,A[6]);  A[7]=fmaf(x1.w,w2v,A[7]);
      A[8]=fmaf(x2.x,w2v,A[8]);  A[9]=fmaf(x2.y,w3v,A[9]);  A[10]=fmaf(x2.z,w3v,A[10]);A[11]=fmaf(x2.w,w3v,A[11]);
      A[12]=fmaf(x3.x,w3v,A[12]);A[13]=fmaf(x3.y,w3v,A[13]);A[14]=fmaf(x3.z,w3v,A[14]);A[15]=fmaf(x3.w,w3v,A[15]);
    }
    float B2[16],B3[16];
    #pragma unroll
    for(int c=0;c<16;c++){ B2[c]=0.f; B3[c]=0.f; }
    tpn_paths<0>(A,A,B2);
    tpn_paths<0>(B2,A,B3);
    float wa=pb0[zz*96+g], wb=pb0[zz*96+32+g], wc=pb0[zz*96+64+g];
    #pragma unroll
    for(int c=0;c<16;c++) sh1[n0*512+g*16+c]=wa*A[c]+wb*B2[c]+wc*B3[c];
  }
  __syncthreads();
  // pblin0 mix (cross-f from sh1) -> feats -> sh2
  if(act){
    float ft[16];
    #pragma unroll
    for(int c=0;c<16;c++) ft[c]=0.f;
    const float* wp=pblin0;
    #pragma unroll 8
    for(int f=0;f<NF;f++){
      const float4* xp=(const float4*)(sh1+n0*512+f*16);
      float4 x0=xp[0],x1=xp[1],x2=xp[2],x3=xp[3];
      float w0v=wp[(f<<5)+g],w1v=wp[1024+(f<<5)+g],w2v=wp[2048+(f<<5)+g],w3v=wp[3072+(f<<5)+g];
      ft[0]=fmaf(x0.x,w0v,ft[0]);  ft[1]=fmaf(x0.y,w1v,ft[1]);  ft[2]=fmaf(x0.z,w1v,ft[2]);  ft[3]=fmaf(x0.w,w1v,ft[3]);
      ft[4]=fmaf(x1.x,w2v,ft[4]);  ft[5]=fmaf(x1.y,w2v,ft[5]);  ft[6]=fmaf(x1.z,w2v,ft[6]);  ft[7]=fmaf(x1.w,w2v,ft[7]);
      ft[8]=fmaf(x2.x,w2v,ft[8]);  ft[9]=fmaf(x2.y,w3v,ft[9]);  ft[10]=fmaf(x2.z,w3v,ft[10]);ft[11]=fmaf(x2.w,w3v,ft[11]);
      ft[12]=fmaf(x3.x,w3v,ft[12]);ft[13]=fmaf(x3.y,w3v,ft[13]);ft[14]=fmaf(x3.z,w3v,ft[14]);ft[15]=fmaf(x3.w,w3v,ft[15]);
    }
    #pragma unroll
    for(int c=0;c<16;c++) sh2[n0*512+g*16+c]=ft[c];
  }
  __syncthreads();
  if(act){
    // readout: resid + e0 from feats scalar channel
    const float* wp=res1+(size_t)zz*1024;
    float a=0.f;
    #pragma unroll 8
    for(int f=0;f<32;f++) a=fmaf(sh2[n0*512+f*16], wp[(f<<5)+g], a);
    resid[(size_t)n*32+g]=a;
    if(g==0){
      float b=0.f;
      #pragma unroll 8
      for(int f=0;f<32;f++) b=fmaf(sh2[n0*512+f*16], ro0[f], b);
      e0[n]=b;
    }
    // up1 mix -> bf16 hl16 (layer-1 hlin)
    float acc[16];
    #pragma unroll
    for(int c=0;c<16;c++) acc[c]=0.f;
    const float* wp2=up1;
    #pragma unroll 8
    for(int f=0;f<NF;f++){
      const float4* xp=(const float4*)(sh2+n0*512+f*16);
      float4 x0=xp[0],x1=xp[1],x2=xp[2],x3=xp[3];
      float w0v=wp2[(f<<5)+g],w1v=wp2[1024+(f<<5)+g],w2v=wp2[2048+(f<<5)+g],w3v=wp2[3072+(f<<5)+g];
      acc[0]=fmaf(x0.x,w0v,acc[0]);  acc[1]=fmaf(x0.y,w1v,acc[1]);  acc[2]=fmaf(x0.z,w1v,acc[2]);  acc[3]=fmaf(x0.w,w1v,acc[3]);
      acc[4]=fmaf(x1.x,w2v,acc[4]);  acc[5]=fmaf(x1.y,w2v,acc[5]);  acc[6]=fmaf(x1.z,w2v,acc[6]);  acc[7]=fmaf(x1.w,w2v,acc[7]);
      acc[8]=fmaf(x2.x,w2v,acc[8]);  acc[9]=fmaf(x2.y,w3v,acc[9]);  acc[10]=fmaf(x2.z,w3v,acc[10]);acc[11]=fmaf(x2.w,w3v,acc[11]);
      acc[12]=fmaf(x3.x,w3v,acc[12]);acc[13]=fmaf(x3.y,w3v,acc[13]);acc[14]=fmaf(x3.z,w3v,acc[14]);acc[15]=fmaf(x3.w,w3v,acc[15]);
    }
    bf16x8 o0,o1;
    #pragma unroll
    for(int c=0;c<8;c++){ o0[c]=(short)f2bf(acc[c]); o1[c]=(short)f2bf(acc[8+c]); }
    bf16x8* op=(bf16x8*)(hl16+(size_t)n*512+g*16);
    op[0]=o0; op[1]=o1;
  }
}

// ---------------- fused layer-1 node chain: lin(post1)+tp_node_sc(pb1)+pblin1+final ----------------
__global__ __launch_bounds__(256) void k_node1(
    const float* __restrict__ agg, const float* __restrict__ post1,
    const float* __restrict__ pb1, const float* __restrict__ pblin1,
    const int* __restrict__ z, const float* __restrict__ resid,
    const float* __restrict__ e0a, const float* __restrict__ ro1a,
    const float* __restrict__ ro1b, float* __restrict__ out, int N)
{
  __shared__ float sh[8*32];
  __shared__ float sh2[8*32];
  __shared__ float red[8];
  int tid=threadIdx.x;
  int n0=tid>>5, g=tid&31;
  int n=blockIdx.x*8+n0;
  bool act=(n<N);
  if(act){
    const float* wp=post1;
    const float* ip=agg+(size_t)n*512;
    float A[16];
    #pragma unroll
    for(int c=0;c<16;c++) A[c]=0.f;
    #pragma unroll 8
    for(int f=0;f<NF;f++){
      const float4* xp=(const float4*)(ip+f*16);
      float4 x0=xp[0],x1=xp[1],x2=xp[2],x3=xp[3];
      float w0v=wp[(f<<5)+g],w1v=wp[1024+(f<<5)+g],w2v=wp[2048+(f<<5)+g],w3v=wp[3072+(f<<5)+g];
      A[0]=fmaf(x0.x,w0v,A[0]);  A[1]=fmaf(x0.y,w1v,A[1]);  A[2]=fmaf(x0.z,w1v,A[2]);  A[3]=fmaf(x0.w,w1v,A[3]);
      A[4]=fmaf(x1.x,w2v,A[4]);  A[5]=fmaf(x1.y,w2v,A[5]);  A[6]=fmaf(x1.z,w2v,A[6]);  A[7]=fmaf(x1.w,w2v,A[7]);
      A[8]=fmaf(x2.x,w2v,A[8]);  A[9]=fmaf(x2.y,w3v,A[9]);  A[10]=fmaf(x2.z,w3v,A[10]);A[11]=fmaf(x2.w,w3v,A[11]);
      A[12]=fmaf(x3.x,w3v,A[12]);A[13]=fmaf(x3.y,w3v,A[13]);A[14]=fmaf(x3.z,w3v,A[14]);A[15]=fmaf(x3.w,w3v,A[15]);
    }
    float B2[16];
    #pragma unroll
    for(int c=0;c<16;c++) B2[c]=0.f;
    tpn_paths<0>(A,A,B2);
    float B3_0=tpn_scalar(B2,A);
    int zz=z[n];
    float wa=pb1[zz*96+g], wb=pb1[zz*96+32+g], wc=pb1[zz*96+64+g];
    sh[n0*32+g]=wa*A[0]+wb*B2[0]+wc*B3_0;
  }
  __syncthreads();
  if(act){
    float a=0.f;
    #pragma unroll 8
    for(int f=0;f<32;f++) a=fmaf(sh[n0*32+f], pblin1[(f<<5)+g], a);
    sh2[n0*32+g]=a+resid[(size_t)n*32+g];
  }
  __syncthreads();
  if(g==0){
    float val=0.f;
    if(act){
      float e1=0.f;
      #pragma unroll
      for(int j=0;j<16;j++){
        float a=0.f;
        #pragma unroll
        for(int f=0;f<32;f++) a=fmaf(sh2[n0*32+f],ro1a[f*16+j],a);
        float s=a/(1.f+__expf(-a));
        e1=fmaf(s,ro1b[j],e1);
      }
      val=-1.5f+2.0f*(e0a[n]+e1)-10.0f;
    }
    red[n0]=val;
  }
  __syncthreads();
  if(tid==0){
    float s=0.f;
    #pragma unroll
    for(int i=0;i<8;i++) s+=red[i];
    atomicAdd(out,s);
  }
}

// ---------------- host orchestration ----------------
extern "C" void kernel_launch(void* const* d_in, const int* in_sizes, int n_in,
                              void* d_out, int out_size, void* d_ws, size_t ws_size,
                              hipStream_t stream)
{
  const float* vec   =(const float*)d_in[0];
  const int*   zarr  =(const int*)  d_in[1];
  const int*   snd   =(const int*)  d_in[2];
  const int*   rcv   =(const int*)  d_in[3];
  const float* embed =(const float*)d_in[4];
  const float* r0w0  =(const float*)d_in[5];
  const float* r0w1  =(const float*)d_in[6];
  const float* r0w2  =(const float*)d_in[7];
  const float* up0   =(const float*)d_in[8];
  const float* post0 =(const float*)d_in[9];
  const float* pb0   =(const float*)d_in[10];
  const float* pblin0=(const float*)d_in[11];
  const float* r1w0  =(const float*)d_in[12];
  const float* r1w1  =(const float*)d_in[13];
  const float* r1w2  =(const float*)d_in[14];
  const float* up1   =(const float*)d_in[15];
  const float* post1 =(const float*)d_in[16];
  const float* pb1   =(const float*)d_in[17];
  const float* pblin1=(const float*)d_in[18];
  const float* sel0  =(const float*)d_in[19];
  const float* ro0   =(const float*)d_in[20];
  const float* res1  =(const float*)d_in[21];
  const float* ro1a  =(const float*)d_in[22];
  const float* ro1b  =(const float*)d_in[23];

  const int E = in_sizes[0]/3;
  const int N = in_sizes[1];
  const int Epad = (E+63)&~63;

  char* ws=(char*)d_ws;
  size_t o=0;
  auto alloc=[&](size_t bytes)->char*{
    char* p=ws+o;
    o=(o+bytes+255)&~(size_t)255;
    return p;
  };
  int*   deg  =(int*)  alloc((size_t)N*4);
  int*   rowp =(int*)  alloc((size_t)(N+1)*4);
  int*   cur  =(int*)  alloc((size_t)N*4);
  int*   eid  =(int*)  alloc((size_t)E*4);
  int*   snd_s=(int*)  alloc((size_t)E*4);
  int*   rcv_s=(int*)  alloc((size_t)E*4);
  float* Yb   =(float*)alloc((size_t)E*16*4);
  float* radb =(float*)alloc((size_t)E*8*4);
  unsigned short* hidb=(unsigned short*)alloc((size_t)(Epad+32)*64*2);
  unsigned short* w2t0=(unsigned short*)alloc((size_t)1088*64*2);
  unsigned short* w2t1=(unsigned short*)alloc((size_t)1088*64*2);
  unsigned short* hl16=(unsigned short*)alloc((size_t)N*512*2);
  float* combw=(float*)alloc((size_t)10*4096*4);
  float* bufB =(float*)alloc((size_t)N*512*4);
  float* bufC =(float*)alloc((size_t)N*512*4);
  float* e0b  =(float*)alloc((size_t)N*4);
  float* residb=(float*)alloc((size_t)N*32*4);

  dim3 tb(256);
  dim3 nblk((unsigned)((N*32+255)/256));
  dim3 n8blk((unsigned)((N+7)/8));
  dim3 eblk((unsigned)((E+255)/256));
  dim3 e32blk((unsigned)((E+31)/32));

  // CSR build (receiver-sorted edge order)
  hipMemsetAsync(deg,0,(size_t)N*4,stream);
  k_count<<<eblk,tb,0,stream>>>(rcv,deg,E);
  k_scan<<<dim3(1),dim3(1024),0,stream>>>(deg,rowp,cur,N);
  k_fill<<<eblk,tb,0,stream>>>(rcv,cur,eid,E);

  k_edge_setup<<<eblk,tb,0,stream>>>(vec,snd,rcv,eid,Yb,radb,snd_s,rcv_s,E);
  k_prep<<<dim3((2*1088*64+10*4096+255)/256),tb,0,stream>>>(r0w2,r1w2,w2t0,w2t1,post0,sel0,combw);
  k_embed16<<<nblk,tb,0,stream>>>(embed,up0,zarr,hl16,N);

  auto run_edges=[&](bool l0, const unsigned short* hlin, const unsigned short* w2t, float* agg){
    hipMemsetAsync(agg,0,(size_t)N*512*4,stream);
    if(l0) k_tp_fused<true ><<<e32blk,tb,0,stream>>>(hlin,Yb,hidb,w2t,snd_s,rcv_s,agg,E);
    else   k_tp_fused<false><<<e32blk,tb,0,stream>>>(hlin,Yb,hidb,w2t,snd_s,rcv_s,agg,E);
  };

  // ---- layer 0 ----
  k_radial<<<eblk,tb,0,stream>>>(radb,r0w0,r0w1,hidb,E);
  run_edges(true,hl16,w2t0,bufB);
  k_node0<<<n8blk,tb,0,stream>>>(bufB,combw,pb0,pblin0,ro0,res1,up1,zarr,e0b,residb,hl16,N);

  // ---- layer 1 ----
  k_radial<<<eblk,tb,0,stream>>>(radb,r1w0,r1w1,hidb,E);
  run_edges(false,hl16,w2t1,bufC);
  hipMemsetAsync(d_out,0,4,stream);
  k_node1<<<n8blk,tb,0,stream>>>(bufC,post1,pb1,pblin1,zarr,residb,e0b,ro1a,ro1b,(float*)d_out,N);
}

// Round 13
// 581.838 us; speedup vs baseline: 2.2808x; 1.0444x over previous
//
#include <hip/hip_runtime.h>
#include <math.h>

// ---------------- static config ----------------
#define NF 32
#define NPATHS 34

typedef __attribute__((ext_vector_type(8))) short bf16x8;
typedef __attribute__((ext_vector_type(4))) float f32x4;
typedef __attribute__((ext_vector_type(2))) float f32x2;

__device__ __forceinline__ unsigned short f2bf(float v){
  unsigned u = __float_as_uint(v);
  u += 0x7fffu + ((u>>16)&1u);
  return (unsigned short)(u>>16);
}
__device__ __forceinline__ float bf2f(unsigned short h){
  return __uint_as_float(((unsigned)h)<<16);
}

struct PathTab { int l1[NPATHS]; int l2[NPATHS]; int l3[NPATHS]; };
constexpr PathTab mkpaths(){
  PathTab t{}; int n=0;
  for(int a=0;a<=3;a++)for(int b=0;b<=3;b++)for(int c=0;c<=3;c++){
    int lo = a>b ? a-b : b-a;
    if(c>=lo && c<=a+b){ t.l1[n]=a; t.l2[n]=b; t.l3[n]=c; n++; }
  }
  return t;
}
constexpr PathTab PT = mkpaths();

// ---------------- compile-time Wigner-3j (exact replica of reference math) ----------------
struct FactT { double v[22]; };
constexpr FactT mkfactT(){ FactT f{}; f.v[0]=1.0; for(int i=1;i<22;i++) f.v[i]=f.v[i-1]*(double)i; return f; }
constexpr FactT FT = mkfactT();
constexpr double cfact(int n){ return FT.v[n]; }

constexpr double csqrt(double x){
  if(x<=0.0) return 0.0;
  double g = x<1.0 ? 1.0 : x;
  for(int i=0;i<40;i++) g=0.5*(g+x/g);
  return g;
}

constexpr double su2cg(int j1,int j2,int j3,int m1,int m2){
  int m3=m1+m2;
  if(m3<-j3||m3>j3) return 0.0;
  double pref = (double)(2*j3+1)*cfact(j3+j1-j2)*cfact(j3-j1+j2)*cfact(j1+j2-j3)/cfact(j1+j2+j3+1);
  pref *= cfact(j3+m3)*cfact(j3-m3)*cfact(j1-m1)*cfact(j1+m1)*cfact(j2-m2)*cfact(j2+m2);
  pref = csqrt(pref);
  int k0=0; if(j2-j3-m1>k0)k0=j2-j3-m1; if(j1-j3+m2>k0)k0=j1-j3+m2;
  int k1=j1+j2-j3; if(j1-m1<k1)k1=j1-m1; if(j2+m2<k1)k1=j2+m2;
  double s=0.0;
  for(int k=k0;k<=k1;k++){
    double d = cfact(k)*cfact(j1+j2-j3-k)*cfact(j1-m1-k)*cfact(j2+m2-k)*cfact(j3-j2+m1+k)*cfact(j3-j1-m2+k);
    s += (k&1)? -1.0/d : 1.0/d;
  }
  return pref*s;
}

struct ccd { double x, y; };
constexpr ccd cqval(int l,int r,int col){
  const double is2 = 0.70710678118654752440;
  double re=0.0, im=0.0;
  if (r<l){ if (col==2*l-r) re=is2; else if (col==r) im=-is2; }
  else if (r==l){ if (col==l) re=1.0; }
  else { double s = ((r-l)&1)? -1.0:1.0;
         if (col==r) re=s*is2; else if (col==2*l-r) im=s*is2; }
  ccd v{re,im};
  switch(l&3){           // multiply by (-i)^l
    case 1: return ccd{ v.y, -v.x };
    case 2: return ccd{-v.x, -v.y };
    case 3: return ccd{-v.y,  v.x };
    default: return v;
  }
}

constexpr double w3entry(int l1,int l2,int l3,int i,int j,int k){
  double re=0.0;
  for(int a=0;a<2*l1+1;a++){
    ccd qa=cqval(l1,a,i); if(qa.x==0.0&&qa.y==0.0) continue;
    for(int b=0;b<2*l2+1;b++){
      ccd qb=cqval(l2,b,j); if(qb.x==0.0&&qb.y==0.0) continue;
      int m1=a-l1, m2=b-l2, m3=m1+m2;
      if(m3<-l3||m3>l3) continue;
      int c=m3+l3;
      double cg=su2cg(l1,l2,l3,m1,m2); if(cg==0.0) continue;
      ccd qc=cqval(l3,c,k); qc.y=-qc.y;   // conj
      if(qc.x==0.0&&qc.y==0.0) continue;
      ccd ab{qa.x*qb.x-qa.y*qb.y, qa.x*qb.y+qa.y*qb.x};
      re += cg*(ab.x*qc.x - ab.y*qc.y);
    }
  }
  return re;
}

template<int L1,int L2,int L3> struct W3Arr { float v[(2*L1+1)*(2*L2+1)*(2*L3+1)]; };
template<int L1,int L2,int L3> constexpr W3Arr<L1,L2,L3> mkW3(double scale){
  W3Arr<L1,L2,L3> r{};
  for(int i=0;i<2*L1+1;i++)
    for(int j=0;j<2*L2+1;j++)
      for(int k=0;k<2*L3+1;k++)
        r.v[(i*(2*L2+1)+j)*(2*L3+1)+k] = (float)(w3entry(L1,L2,L3,i,j,k)*scale);
  return r;
}
template<int L1,int L2,int L3> constexpr W3Arr<L1,L2,L3> W3V = mkW3<L1,L2,L3>(1.0);
template<int L1,int L2,int L3> constexpr W3Arr<L1,L2,L3> W3N = mkW3<L1,L2,L3>(1.0/csqrt(2.0*L3+1.0));

// SH recursion scales (replica of reference _sh_scales, float64 like numpy)
struct SCt { double sc2, sc3; };
constexpr SCt mksc(){
  double v0=0.2,v1=-0.6,v2=0.7;
  double nv=csqrt(v0*v0+v1*v1+v2*v2);
  double s3=csqrt(3.0);
  double y1[3]={s3*v0/nv, s3*v1/nv, s3*v2/nv};
  double t2[5]={0,0,0,0,0}; double n2=0.0;
  for(int c=0;c<5;c++){
    double s=0.0;
    for(int a=0;a<3;a++)for(int b=0;b<3;b++) s += w3entry(1,1,2,a,b,c)*y1[a]*y1[b];
    t2[c]=s; n2+=s*s;
  }
  double sc2=csqrt(5.0)/csqrt(n2);
  double y2[5]={sc2*t2[0],sc2*t2[1],sc2*t2[2],sc2*t2[3],sc2*t2[4]};
  double n3=0.0;
  for(int c=0;c<7;c++){
    double s=0.0;
    for(int a=0;a<5;a++)for(int b=0;b<3;b++) s += w3entry(2,1,3,a,b,c)*y2[a]*y1[b];
    n3+=s*s;
  }
  double sc3=csqrt(7.0)/csqrt(n3);
  return SCt{sc2,sc3};
}
constexpr SCt SCV = mksc();

// ---------------- scalar template-unrolled TP with literal W3J (node kernels + SH) ----------------
template<bool NORM,int l1,int l2,int l3,int A,int B,int C>
__device__ __forceinline__ void w3term(const float* __restrict__ x, const float* __restrict__ y,
                                       float rv, float* __restrict__ acc){
  constexpr float w = NORM ? W3N<l1,l2,l3>.v[(A*(2*l2+1)+B)*(2*l3+1)+C]
                           : W3V<l1,l2,l3>.v[(A*(2*l2+1)+B)*(2*l3+1)+C];
  if constexpr (w!=0.0f)
    acc[l3*l3+C] = fmaf(w, x[l1*l1+A]*y[l2*l2+B]*rv, acc[l3*l3+C]);
}
template<bool NORM,int l1,int l2,int l3,int A,int B,int C>
__device__ __forceinline__ void w3loopC(const float* x,const float* y,float rv,float* acc){
  if constexpr (C<2*l3+1){
    w3term<NORM,l1,l2,l3,A,B,C>(x,y,rv,acc);
    w3loopC<NORM,l1,l2,l3,A,B,C+1>(x,y,rv,acc);
  }
}
template<bool NORM,int l1,int l2,int l3,int A,int B>
__device__ __forceinline__ void w3loopB(const float* x,const float* y,float rv,float* acc){
  if constexpr (B<2*l2+1){
    w3loopC<NORM,l1,l2,l3,A,B,0>(x,y,rv,acc);
    w3loopB<NORM,l1,l2,l3,A,B+1>(x,y,rv,acc);
  }
}
template<bool NORM,int l1,int l2,int l3,int A>
__device__ __forceinline__ void w3loopA(const float* x,const float* y,float rv,float* acc){
  if constexpr (A<2*l1+1){
    w3loopB<NORM,l1,l2,l3,A,0>(x,y,rv,acc);
    w3loopA<NORM,l1,l2,l3,A+1>(x,y,rv,acc);
  }
}

template<int P>
__device__ __forceinline__ void tpn_paths(const float* x,const float* y,float* o){
  if constexpr (P<NPATHS){
    constexpr int l1=PT.l1[P], l2=PT.l2[P], l3=PT.l3[P];
    w3loopA<true,l1,l2,l3,0>(x,y,1.0f,o);
    tpn_paths<P+1>(x,y,o);
  }
}

// scalar-only node TP: l3=0 paths (l,l,0) only
__device__ __forceinline__ float tpn_scalar(const float* x,const float* y){
  float o[1]={0.f};
  w3loopA<true,0,0,0,0>(x,y,1.0f,o);
  w3loopA<true,1,1,0,0>(x,y,1.0f,o);
  w3loopA<true,2,2,0,0>(x,y,1.0f,o);
  w3loopA<true,3,3,0,0>(x,y,1.0f,o);
  return o[0];
}

// ---------------- packed-pair (two edges per thread, f32x2 -> v_pk_fma_f32) TP ----------------
template<int l1,int l2,int l3,int A,int B>
constexpr bool anyNZ(){
  for(int c=0;c<2*l3+1;c++)
    if(W3V<l1,l2,l3>.v[(A*(2*l2+1)+B)*(2*l3+1)+c]!=0.0f) return true;
  return false;
}
template<int l1,int l2,int l3,int A,int B,int C>
__device__ __forceinline__ void w3C2(const f32x2 p, f32x2* __restrict__ S){
  constexpr float w = W3V<l1,l2,l3>.v[(A*(2*l2+1)+B)*(2*l3+1)+C];
  if constexpr (w!=0.0f) S[C] = p*w + S[C];
  if constexpr (C+1<2*l3+1) w3C2<l1,l2,l3,A,B,C+1>(p,S);
}
template<int l1,int l2,int l3,int A,int B>
__device__ __forceinline__ void w3B2(const f32x2* __restrict__ x,const f32x2* __restrict__ y,
                                     f32x2* __restrict__ S){
  if constexpr (anyNZ<l1,l2,l3,A,B>()){
    f32x2 p = x[l1*l1+A]*y[l2*l2+B];
    w3C2<l1,l2,l3,A,B,0>(p,S);
  }
  if constexpr (B+1<2*l2+1) w3B2<l1,l2,l3,A,B+1>(x,y,S);
}
template<int l1,int l2,int l3,int A>
__device__ __forceinline__ void w3A2(const f32x2* __restrict__ x,const f32x2* __restrict__ y,
                                     f32x2* __restrict__ S){
  w3B2<l1,l2,l3,A,0>(x,y,S);
  if constexpr (A+1<2*l1+1) w3A2<l1,l2,l3,A+1>(x,y,S);
}
// R21 layout: rws element (P,f,le) at u16 index (P*32+f)*18 + le.
// rp = rws + f*18 + le0; path P -> rp[P*576] (edge A) and rp[P*576+4] (edge B, le1=le0+4).
// f-lanes stride 36B = 9 dwords, gcd(9,32)=1 -> all 32 banks; half-wave pairing 2-way (free).
template<bool L0,int P>
__device__ __forceinline__ void tp2(const f32x2* __restrict__ x,const f32x2* __restrict__ y,
                                    const unsigned short* __restrict__ rp,
                                    f32x2* __restrict__ acc){
  if constexpr (P<NPATHS){
    constexpr int l1=PT.l1[P], l2=PT.l2[P], l3=PT.l3[P];
    if constexpr (!(L0 && l1!=0)){
      f32x2 S[2*l3+1];
      #pragma unroll
      for(int c=0;c<2*l3+1;c++) S[c]=(f32x2){0.f,0.f};
      w3A2<l1,l2,l3,0>(x,y,S);
      f32x2 rv = { bf2f(rp[P*576]), bf2f(rp[P*576+4]) };
      #pragma unroll
      for(int c=0;c<2*l3+1;c++) acc[l3*l3+c] = rv*S[c] + acc[l3*l3+c];
    }
    tp2<L0,P+1>(x,y,rp,acc);
  }
}

// ---------------- CSR build: degree count, scan, fill ----------------
__global__ __launch_bounds__(256) void k_count(
    const int* __restrict__ rcv, int* __restrict__ deg, int E)
{
  int e=blockIdx.x*256+threadIdx.x;
  if(e>=E) return;
  atomicAdd(&deg[rcv[e]],1);
}

#define SCAN_PER 32
__global__ __launch_bounds__(1024) void k_scan(
    const int* __restrict__ deg, int* __restrict__ row,
    int* __restrict__ cur, int N)
{
  __shared__ int part[1024];
  int t=threadIdx.x;
  int per=(N+1023)/1024; if(per>SCAN_PER) per=SCAN_PER;
  int base=t*per;
  int loc[SCAN_PER];
  int s=0;
  for(int i=0;i<per;i++){ int idx=base+i; int v=(idx<N)? deg[idx]:0; loc[i]=s; s+=v; }
  part[t]=s;
  __syncthreads();
  for(int off=1;off<1024;off<<=1){
    int v=(t>=off)? part[t-off]:0;
    __syncthreads();
    part[t]+=v;
    __syncthreads();
  }
  int ex=(t==0)?0:part[t-1];
  for(int i=0;i<per;i++){
    int idx=base+i;
    if(idx<N){ int r=ex+loc[i]; row[idx]=r; cur[idx]=r; }
  }
  if(t==1023) row[N]=part[1023];
}

__global__ __launch_bounds__(256) void k_fill(
    const int* __restrict__ rcv, int* __restrict__ cur,
    int* __restrict__ eid, int E)
{
  int e=blockIdx.x*256+threadIdx.x;
  if(e>=E) return;
  int pos=atomicAdd(&cur[rcv[e]],1);
  eid[pos]=e;
}

// ---------------- per-edge geometry (receiver-sorted order): SH + radial basis ----------------
__global__ __launch_bounds__(256) void k_edge_setup(
    const float* __restrict__ vec, const int* __restrict__ snd,
    const int* __restrict__ rcv, const int* __restrict__ eid,
    float* __restrict__ Y, float* __restrict__ rad,
    int* __restrict__ snd_s, int* __restrict__ rcv_s, int E)
{
  int j = blockIdx.x*256+threadIdx.x;
  if (j>=E) return;
  int e = eid[j];
  snd_s[j]=snd[e];
  rcv_s[j]=rcv[e];
  float vx=vec[3*e], vy=vec[3*e+1], vz=vec[3*e+2];
  float r=sqrtf(vx*vx+vy*vy+vz*vz);
  float inv=1.0f/fmaxf(r,1e-9f);
  float y[16];
  y[0]=1.0f;
  const float s3=1.7320508075688772f;
  y[1]=s3*vx*inv; y[2]=s3*vy*inv; y[3]=s3*vz*inv;
  constexpr float sc2=(float)SCV.sc2, sc3=(float)SCV.sc3;
  {
    float t[16];
    #pragma unroll
    for(int c=0;c<16;c++) t[c]=0.f;
    w3loopA<false,1,1,2,0>(y,y,1.0f,t);
    #pragma unroll
    for(int c=0;c<5;c++) y[4+c]=sc2*t[4+c];
    w3loopA<false,2,1,3,0>(y,y,1.0f,t);
    #pragma unroll
    for(int c=0;c<7;c++) y[9+c]=sc3*t[9+c];
  }
  float4* Yp=(float4*)(Y+(size_t)j*16);
  Yp[0]=make_float4(y[0],y[1],y[2],y[3]);
  Yp[1]=make_float4(y[4],y[5],y[6],y[7]);
  Yp[2]=make_float4(y[8],y[9],y[10],y[11]);
  Yp[3]=make_float4(y[12],y[13],y[14],y[15]);
  float x = r*0.2f;
  float env=0.f;
  if (x<1.0f){
    float x2=x*x; float x4=x2*x2; float x5=x4*x;
    env = 1.0f - 21.0f*x5 + 35.0f*x5*x - 15.0f*x5*x2;
  }
  const float cb = 0.632455532033675866f; // sqrt(2/5)
  float base = inv*env*cb;
  #pragma unroll
  for(int n=1;n<=8;n++)
    rad[(size_t)j*8 + n-1] = base*sinf(3.14159265358979323846f * x * (float)n);
}

// ---------------- layer-0 hlin directly from scalar embedding (bf16) ----------------
__global__ __launch_bounds__(256) void k_embed16(
    const float* __restrict__ embed, const float* __restrict__ up0,
    const int* __restrict__ z, unsigned short* __restrict__ hl16, int N)
{
  int t=blockIdx.x*256+threadIdx.x;
  int n=t>>5, g=t&31;
  if(n>=N) return;
  const float* ep=embed+z[n]*32;
  float a=0.f;
  #pragma unroll 8
  for(int f=0;f<32;f++) a=fmaf(ep[f],up0[(f<<5)+g],a);
  bf16x8 o0={(short)f2bf(a),0,0,0,0,0,0,0};
  bf16x8 o1={0,0,0,0,0,0,0,0};
  bf16x8* op=(bf16x8*)(hl16+(size_t)n*512+g*16);
  op[0]=o0; op[1]=o1;
}

// ---------------- radial MLP hidden layers (bf16 output) ----------------
__global__ __launch_bounds__(256) void k_radial(
    const float* __restrict__ rad, const float* __restrict__ w0,
    const float* __restrict__ w1, unsigned short* __restrict__ hid, int E)
{
  __shared__ float w0s[8*64];
  __shared__ float w1s[64*64];
  int tid=threadIdx.x;
  for(int i=tid;i<512;i+=256) w0s[i]=w0[i];
  for(int i=tid;i<4096;i+=256) w1s[i]=w1[i];
  __syncthreads();
  int e=blockIdx.x*256+tid;
  if(e>=E) return;
  const float4* rp=(const float4*)(rad+(size_t)e*8);
  float4 ra=rp[0], rb=rp[1];
  float rv[8]={ra.x,ra.y,ra.z,ra.w,rb.x,rb.y,rb.z,rb.w};
  float h1[64];
  #pragma unroll 8
  for(int j=0;j<64;j++){
    float a=0.f;
    #pragma unroll
    for(int i=0;i<8;i++) a=fmaf(rv[i],w0s[i*64+j],a);
    h1[j]=a/(1.f+__expf(-a));
  }
  unsigned short* hp = hid+(size_t)e*64;
  #pragma unroll 4
  for(int j=0;j<64;j++){
    float a=0.f;
    #pragma unroll
    for(int i=0;i<64;i++) a=fmaf(h1[i],w1s[i*64+j],a);
    hp[j]=f2bf(a/(1.f+__expf(-a)));
  }
}

// ---------------- weight prep: cast+transpose both w2, and comb = post0@sel0 ----------------
__global__ __launch_bounds__(256) void k_prep(
    const float* __restrict__ w2a, const float* __restrict__ w2b,
    unsigned short* __restrict__ ta, unsigned short* __restrict__ tb,
    const float* __restrict__ post0, const float* __restrict__ sel0,
    float* __restrict__ comb)
{
  int t=blockIdx.x*256+threadIdx.x;
  const int C2=2*1088*64;
  if(t<C2){
    const float* src = (t<1088*64)? w2a : w2b;
    unsigned short* dst = (t<1088*64)? ta : tb;
    int u = (t<1088*64)? t : t-1088*64;
    int c=u>>6, k=u&63;
    dst[(size_t)c*64+k]=f2bf(src[(size_t)k*1088+c]);
  } else {
    int u=t-C2;
    if(u<10*4096){
      int z=u>>12, r=u&4095;
      int l=r>>10, e=(r>>5)&31, g=r&31;
      const float* pp=post0+l*1024+e*32;
      const float* sp=sel0+(size_t)z*4096+l*1024;
      float a=0.f;
      #pragma unroll 8
      for(int f=0;f<32;f++) a=fmaf(pp[f], sp[f*32+g], a);
      comb[(size_t)z*4096 + l*1024 + e*32 + g]=a;
    }
  }
}

// ---------------- FUSED: MFMA rw-GEMM (LDS) + packed-pair edge TP + in-block segment reduce ----------------
// R23 verified best (583.7us total). Session ladder: 767 -> 615.9 (R14 pk-pair + transposed
// rw LDS) -> 604.5 (R21 [P][f][le] packed write path) -> 589.8 (R22 in-block segment reduce,
// seg_sum+msgs round-trip deleted) -> 583.7 (R23 stride-17 lmsg staging). R24 (radial
// fusion: latency-chain poisoning) and R25 (32-edge blocks: occupancy loss > w2t savings)
// both regressed and were reverted. This is R23 byte-exact.
template<bool L0>
__global__ __launch_bounds__(256,3) void k_tp_fused(
    const unsigned short* __restrict__ hlin, const float* __restrict__ Y,
    const unsigned short* __restrict__ hid, const unsigned short* __restrict__ w2t,
    const int* __restrict__ snd_s, const int* __restrict__ rcv_s,
    float* __restrict__ agg, int eb, int ecnt)
{
  constexpr int NT  = L0 ? 8 : 68;      // 16-wide col tiles of the rw GEMM
  constexpr int PD  = L0 ? 4 : 34;      // P dim of rws
  constexpr int RWSU = PD*32*18;        // u16 in the rw strip
  constexpr int LMU  = 8704*2;          // u16 backing 512x17 f32 lmsg (stride-17 pad)
  constexpr int LDSU = RWSU > LMU ? RWSU : LMU;
  __shared__ unsigned short rws[LDSU] __attribute__((aligned(16)));
  __shared__ int r16v[16];
  int tid=threadIdx.x;
  int lane=tid&63, wave=tid>>6;
  int m16=lane&15, quad=lane>>4;
  int el0=blockIdx.x*16;
  int f=tid&31;
  int hb=(tid>>5)&1;
  int le_base = wave + hb*8;
  int el_s0 = el0 + le_base;
  int el_s1 = el0 + le_base + 4;
  bool actA = el_s0<ecnt, okB = el_s1<ecnt;
  int s0 = actA ? snd_s[eb+el_s0] : 0;
  int s1 = okB  ? snd_s[eb+el_s1] : 0;
  if(tid<16) r16v[tid] = (el0+tid<ecnt) ? rcv_s[eb+el0+tid] : -1;
  // ---- phase 1: rw GEMM, store [P][f][le] as packed bf16 pairs ----
  {
    const unsigned short* Ab = hid + (size_t)el0*64;
    bf16x8 a0 = *(const bf16x8*)(Ab + m16*64 + quad*8);
    bf16x8 a1 = *(const bf16x8*)(Ab + m16*64 + 32 + quad*8);
    #pragma unroll 2
    for(int nt=wave; nt<NT; nt+=4){
      int col = nt*16 + m16;
      bf16x8 b0 = *(const bf16x8*)(w2t + (size_t)col*64 + quad*8);
      bf16x8 b1 = *(const bf16x8*)(w2t + (size_t)col*64 + 32 + quad*8);
      f32x4 acc = (f32x4){0.f,0.f,0.f,0.f};
      acc = __builtin_amdgcn_mfma_f32_16x16x32_bf16(a0,b0,acc,0,0,0);
      acc = __builtin_amdgcn_mfma_f32_16x16x32_bf16(a1,b1,acc,0,0,0);
      int fc = col&31, P = col>>5;
      unsigned w0 = (unsigned)f2bf(acc[0]) | ((unsigned)f2bf(acc[1])<<16);
      unsigned w1 = (unsigned)f2bf(acc[2]) | ((unsigned)f2bf(acc[3])<<16);
      unsigned* wp = (unsigned*)(rws + (size_t)(P*32+fc)*18 + quad*4);
      wp[0]=w0; wp[1]=w1;
    }
  }
  __syncthreads();
  // ---- phase 2: packed-pair TP for edges (el_s0, el_s1) ----
  size_t jA = actA ? (size_t)(eb+el_s0) : 0;
  size_t jB = okB  ? (size_t)(eb+el_s1) : 0;
  f32x2 hs[16];
  if constexpr (L0){
    hs[0] = (f32x2){ bf2f(hlin[(size_t)s0*512 + f*16]),
                     bf2f(hlin[(size_t)s1*512 + f*16]) };
  } else {
    const bf16x8* hA = (const bf16x8*)(hlin + (size_t)s0*512 + f*16);
    const bf16x8* hB = (const bf16x8*)(hlin + (size_t)s1*512 + f*16);
    bf16x8 ha0=hA[0], ha1=hA[1], hb0=hB[0], hb1=hB[1];
    #pragma unroll
    for(int c=0;c<8;c++){
      hs[c]   = (f32x2){ bf2f((unsigned short)ha0[c]), bf2f((unsigned short)hb0[c]) };
      hs[8+c] = (f32x2){ bf2f((unsigned short)ha1[c]), bf2f((unsigned short)hb1[c]) };
    }
  }
  f32x2 yv[16];
  {
    const float4* yA=(const float4*)(Y+jA*16);
    const float4* yB=(const float4*)(Y+jB*16);
    float4 a0=yA[0],a1=yA[1],a2=yA[2],a3=yA[3];
    float4 b0=yB[0],b1=yB[1],b2=yB[2],b3=yB[3];
    yv[0]=(f32x2){a0.x,b0.x}; yv[1]=(f32x2){a0.y,b0.y}; yv[2]=(f32x2){a0.z,b0.z}; yv[3]=(f32x2){a0.w,b0.w};
    yv[4]=(f32x2){a1.x,b1.x}; yv[5]=(f32x2){a1.y,b1.y}; yv[6]=(f32x2){a1.z,b1.z}; yv[7]=(f32x2){a1.w,b1.w};
    yv[8]=(f32x2){a2.x,b2.x}; yv[9]=(f32x2){a2.y,b2.y}; yv[10]=(f32x2){a2.z,b2.z}; yv[11]=(f32x2){a2.w,b2.w};
    yv[12]=(f32x2){a3.x,b3.x}; yv[13]=(f32x2){a3.y,b3.y}; yv[14]=(f32x2){a3.z,b3.z}; yv[15]=(f32x2){a3.w,b3.w};
  }
  const unsigned short* rp = rws + f*18 + le_base;
  f32x2 acc[16];
  #pragma unroll
  for(int c=0;c<16;c++) acc[c]=(f32x2){0.f,0.f};
  tp2<L0,0>(hs,yv,rp,acc);
  // ---- phase 3: stage f32 messages in LDS (stride-17 rows), segment-reduce, atomicAdd ----
  __syncthreads();                       // all tp2 LDS reads done; safe to overwrite
  float* lm = (float*)rws;               // lmsg[(le*32+f)*17 + c]
  if(actA){
    #pragma unroll
    for(int c=0;c<16;c++) lm[(le_base*32+f)*17+c] = acc[c].x*0.0625f;
  }
  if(okB){
    #pragma unroll
    for(int c=0;c<16;c++) lm[((le_base+4)*32+f)*17+c] = acc[c].y*0.0625f;
  }
  __syncthreads();
  #pragma unroll
  for(int s=tid; s<512; s+=256){
    int ff=s>>4, cc=s&15;
    float run=0.f; int cur=-1;
    #pragma unroll
    for(int le=0; le<16; le++){
      int rr = r16v[le];
      if(rr != cur){
        if(cur >= 0) atomicAdd(agg + (size_t)cur*512 + s, run);
        run = 0.f; cur = rr;
      }
      if(rr >= 0) run += lm[(le*32+ff)*17 + cc];
    }
    if(cur >= 0) atomicAdd(agg + (size_t)cur*512 + s, run);
  }
}

// ---------------- fused layer-0 node chain: lin(comb)+tp_node(pb0)+pblin0+readout+up1->hl16 ----------------
__global__ __launch_bounds__(256) void k_node0(
    const float* __restrict__ agg, const float* __restrict__ combw,
    const float* __restrict__ pb0, const float* __restrict__ pblin0,
    const float* __restrict__ ro0, const float* __restrict__ res1,
    const float* __restrict__ up1, const int* __restrict__ z,
    float* __restrict__ e0, float* __restrict__ resid,
    unsigned short* __restrict__ hl16, int N)
{
  __shared__ float sh1[8*512] __attribute__((aligned(16)));
  __shared__ float sh2[8*512] __attribute__((aligned(16)));
  int tid=threadIdx.x;
  int n0=tid>>5, g=tid&31;
  int n=blockIdx.x*8+n0;
  bool act=(n<N);
  int zz = act? z[n] : 0;
  if(act){
    const float* wp = combw + (size_t)zz*4096;
    const float* ip = agg + (size_t)n*512;
    float A[16];
    #pragma unroll
    for(int c=0;c<16;c++) A[c]=0.f;
    #pragma unroll 8
    for(int f=0;f<NF;f++){
      const float4* xp=(const float4*)(ip+f*16);
      float4 x0=xp[0],x1=xp[1],x2=xp[2],x3=xp[3];
      float w0v=wp[(f<<5)+g],w1v=wp[1024+(f<<5)+g],w2v=wp[2048+(f<<5)+g],w3v=wp[3072+(f<<5)+g];
      A[0]=fmaf(x0.x,w0v,A[0]);  A[1]=fmaf(x0.y,w1v,A[1]);  A[2]=fmaf(x0.z,w1v,A[2]);  A[3]=fmaf(x0.w,w1v,A[3]);
      A[4]=fmaf(x1.x,w2v,A[4]);  A[5]=fmaf(x1.y,w2v,A[5]);  A[6]=fmaf(x1.z,w2v,A[6]);  A[7]=fmaf(x1.w,w2v,A[7]);
      A[8]=fmaf(x2.x,w2v,A[8]);  A[9]=fmaf(x2.y,w3v,A[9]);  A[10]=fmaf(x2.z,w3v,A[10]);A[11]=fmaf(x2.w,w3v,A[11]);
      A[12]=fmaf(x3.x,w3v,A[12]);A[13]=fmaf(x3.y,w3v,A[13]);A[14]=fmaf(x3.z,w3v,A[14]);A[15]=fmaf(x3.w,w3v,A[15]);
    }
    float B2[16],B3[16];
    #pragma unroll
    for(int c=0;c<16;c++){ B2[c]=0.f; B3[c]=0.f; }
    tpn_paths<0>(A,A,B2);
    tpn_paths<0>(B2,A,B3);
    float wa=pb0[zz*96+g], wb=pb0[zz*96+32+g], wc=pb0[zz*96+64+g];
    #pragma unroll
    for(int c=0;c<16;c++) sh1[n0*512+g*16+c]=wa*A[c]+wb*B2[c]+wc*B3[c];
  }
  __syncthreads();
  // pblin0 mix (cross-f from sh1) -> feats -> sh2
  if(act){
    float ft[16];
    #pragma unroll
    for(int c=0;c<16;c++) ft[c]=0.f;
    const float* wp=pblin0;
    #pragma unroll 8
    for(int f=0;f<NF;f++){
      const float4* xp=(const float4*)(sh1+n0*512+f*16);
      float4 x0=xp[0],x1=xp[1],x2=xp[2],x3=xp[3];
      float w0v=wp[(f<<5)+g],w1v=wp[1024+(f<<5)+g],w2v=wp[2048+(f<<5)+g],w3v=wp[3072+(f<<5)+g];
      ft[0]=fmaf(x0.x,w0v,ft[0]);  ft[1]=fmaf(x0.y,w1v,ft[1]);  ft[2]=fmaf(x0.z,w1v,ft[2]);  ft[3]=fmaf(x0.w,w1v,ft[3]);
      ft[4]=fmaf(x1.x,w2v,ft[4]);  ft[5]=fmaf(x1.y,w2v,ft[5]);  ft[6]=fmaf(x1.z,w2v,ft[6]);  ft[7]=fmaf(x1.w,w2v,ft[7]);
      ft[8]=fmaf(x2.x,w2v,ft[8]);  ft[9]=fmaf(x2.y,w3v,ft[9]);  ft[10]=fmaf(x2.z,w3v,ft[10]);ft[11]=fmaf(x2.w,w3v,ft[11]);
      ft[12]=fmaf(x3.x,w3v,ft[12]);ft[13]=fmaf(x3.y,w3v,ft[13]);ft[14]=fmaf(x3.z,w3v,ft[14]);ft[15]=fmaf(x3.w,w3v,ft[15]);
    }
    #pragma unroll
    for(int c=0;c<16;c++) sh2[n0*512+g*16+c]=ft[c];
  }
  __syncthreads();
  if(act){
    // readout: resid + e0 from feats scalar channel
    const float* wp=res1+(size_t)zz*1024;
    float a=0.f;
    #pragma unroll 8
    for(int f=0;f<32;f++) a=fmaf(sh2[n0*512+f*16], wp[(f<<5)+g], a);
    resid[(size_t)n*32+g]=a;
    if(g==0){
      float b=0.f;
      #pragma unroll 8
      for(int f=0;f<32;f++) b=fmaf(sh2[n0*512+f*16], ro0[f], b);
      e0[n]=b;
    }
    // up1 mix -> bf16 hl16 (layer-1 hlin)
    float acc[16];
    #pragma unroll
    for(int c=0;c<16;c++) acc[c]=0.f;
    const float* wp2=up1;
    #pragma unroll 8
    for(int f=0;f<NF;f++){
      const float4* xp=(const float4*)(sh2+n0*512+f*16);
      float4 x0=xp[0],x1=xp[1],x2=xp[2],x3=xp[3];
      float w0v=wp2[(f<<5)+g],w1v=wp2[1024+(f<<5)+g],w2v=wp2[2048+(f<<5)+g],w3v=wp2[3072+(f<<5)+g];
      acc[0]=fmaf(x0.x,w0v,acc[0]);  acc[1]=fmaf(x0.y,w1v,acc[1]);  acc[2]=fmaf(x0.z,w1v,acc[2]);  acc[3]=fmaf(x0.w,w1v,acc[3]);
      acc[4]=fmaf(x1.x,w2v,acc[4]);  acc[5]=fmaf(x1.y,w2v,acc[5]);  acc[6]=fmaf(x1.z,w2v,acc[6]);  acc[7]=fmaf(x1.w,w2v,acc[7]);
      acc[8]=fmaf(x2.x,w2v,acc[8]);  acc[9]=fmaf(x2.y,w3v,acc[9]);  acc[10]=fmaf(x2.z,w3v,acc[10]);acc[11]=fmaf(x2.w,w3v,acc[11]);
      acc[12]=fmaf(x3.x,w3v,acc[12]);acc[13]=fmaf(x3.y,w3v,acc[13]);acc[14]=fmaf(x3.z,w3v,acc[14]);acc[15]=fmaf(x3.w,w3v,acc[15]);
    }
    bf16x8 o0,o1;
    #pragma unroll
    for(int c=0;c<8;c++){ o0[c]=(short)f2bf(acc[c]); o1[c]=(short)f2bf(acc[8+c]); }
    bf16x8* op=(bf16x8*)(hl16+(size_t)n*512+g*16);
    op[0]=o0; op[1]=o1;
  }
}

// ---------------- fused layer-1 node chain: lin(post1)+tp_node_sc(pb1)+pblin1+final ----------------
__global__ __launch_bounds__(256) void k_node1(
    const float* __restrict__ agg, const float* __restrict__ post1,
    const float* __restrict__ pb1, const float* __restrict__ pblin1,
    const int* __restrict__ z, const float* __restrict__ resid,
    const float* __restrict__ e0a, const float* __restrict__ ro1a,
    const float* __restrict__ ro1b, float* __restrict__ out, int N)
{
  __shared__ float sh[8*32];
  __shared__ float sh2[8*32];
  __shared__ float red[8];
  int tid=threadIdx.x;
  int n0=tid>>5, g=tid&31;
  int n=blockIdx.x*8+n0;
  bool act=(n<N);
  if(act){
    const float* wp=post1;
    const float* ip=agg+(size_t)n*512;
    float A[16];
    #pragma unroll
    for(int c=0;c<16;c++) A[c]=0.f;
    #pragma unroll 8
    for(int f=0;f<NF;f++){
      const float4* xp=(const float4*)(ip+f*16);
      float4 x0=xp[0],x1=xp[1],x2=xp[2],x3=xp[3];
      float w0v=wp[(f<<5)+g],w1v=wp[1024+(f<<5)+g],w2v=wp[2048+(f<<5)+g],w3v=wp[3072+(f<<5)+g];
      A[0]=fmaf(x0.x,w0v,A[0]);  A[1]=fmaf(x0.y,w1v,A[1]);  A[2]=fmaf(x0.z,w1v,A[2]);  A[3]=fmaf(x0.w,w1v,A[3]);
      A[4]=fmaf(x1.x,w2v,A[4]);  A[5]=fmaf(x1.y,w2v,A[5]);  A[6]=fmaf(x1.z,w2v,A[6]);  A[7]=fmaf(x1.w,w2v,A[7]);
      A[8]=fmaf(x2.x,w2v,A[8]);  A[9]=fmaf(x2.y,w3v,A[9]);  A[10]=fmaf(x2.z,w3v,A[10]);A[11]=fmaf(x2.w,w3v,A[11]);
      A[12]=fmaf(x3.x,w3v,A[12]);A[13]=fmaf(x3.y,w3v,A[13]);A[14]=fmaf(x3.z,w3v,A[14]);A[15]=fmaf(x3.w,w3v,A[15]);
    }
    float B2[16];
    #pragma unroll
    for(int c=0;c<16;c++) B2[c]=0.f;
    tpn_paths<0>(A,A,B2);
    float B3_0=tpn_scalar(B2,A);
    int zz=z[n];
    float wa=pb1[zz*96+g], wb=pb1[zz*96+32+g], wc=pb1[zz*96+64+g];
    sh[n0*32+g]=wa*A[0]+wb*B2[0]+wc*B3_0;
  }
  __syncthreads();
  if(act){
    float a=0.f;
    #pragma unroll 8
    for(int f=0;f<32;f++) a=fmaf(sh[n0*32+f], pblin1[(f<<5)+g], a);
    sh2[n0*32+g]=a+resid[(size_t)n*32+g];
  }
  __syncthreads();
  if(g==0){
    float val=0.f;
    if(act){
      float e1=0.f;
      #pragma unroll
      for(int j=0;j<16;j++){
        float a=0.f;
        #pragma unroll
        for(int f=0;f<32;f++) a=fmaf(sh2[n0*32+f],ro1a[f*16+j],a);
        float s=a/(1.f+__expf(-a));
        e1=fmaf(s,ro1b[j],e1);
      }
      val=-1.5f+2.0f*(e0a[n]+e1)-10.0f;
    }
    red[n0]=val;
  }
  __syncthreads();
  if(tid==0){
    float s=0.f;
    #pragma unroll
    for(int i=0;i<8;i++) s+=red[i];
    atomicAdd(out,s);
  }
}

// ---------------- host orchestration ----------------
extern "C" void kernel_launch(void* const* d_in, const int* in_sizes, int n_in,
                              void* d_out, int out_size, void* d_ws, size_t ws_size,
                              hipStream_t stream)
{
  const float* vec   =(const float*)d_in[0];
  const int*   zarr  =(const int*)  d_in[1];
  const int*   snd   =(const int*)  d_in[2];
  const int*   rcv   =(const int*)  d_in[3];
  const float* embed =(const float*)d_in[4];
  const float* r0w0  =(const float*)d_in[5];
  const float* r0w1  =(const float*)d_in[6];
  const float* r0w2  =(const float*)d_in[7];
  const float* up0   =(const float*)d_in[8];
  const float* post0 =(const float*)d_in[9];
  const float* pb0   =(const float*)d_in[10];
  const float* pblin0=(const float*)d_in[11];
  const float* r1w0  =(const float*)d_in[12];
  const float* r1w1  =(const float*)d_in[13];
  const float* r1w2  =(const float*)d_in[14];
  const float* up1   =(const float*)d_in[15];
  const float* post1 =(const float*)d_in[16];
  const float* pb1   =(const float*)d_in[17];
  const float* pblin1=(const float*)d_in[18];
  const float* sel0  =(const float*)d_in[19];
  const float* ro0   =(const float*)d_in[20];
  const float* res1  =(const float*)d_in[21];
  const float* ro1a  =(const float*)d_in[22];
  const float* ro1b  =(const float*)d_in[23];

  const int E = in_sizes[0]/3;
  const int N = in_sizes[1];
  const int Epad = (E+63)&~63;

  char* ws=(char*)d_ws;
  size_t o=0;
  auto alloc=[&](size_t bytes)->char*{
    char* p=ws+o;
    o=(o+bytes+255)&~(size_t)255;
    return p;
  };
  int*   deg  =(int*)  alloc((size_t)N*4);
  int*   rowp =(int*)  alloc((size_t)(N+1)*4);
  int*   cur  =(int*)  alloc((size_t)N*4);
  int*   eid  =(int*)  alloc((size_t)E*4);
  int*   snd_s=(int*)  alloc((size_t)E*4);
  int*   rcv_s=(int*)  alloc((size_t)E*4);
  float* Yb   =(float*)alloc((size_t)E*16*4);
  float* radb =(float*)alloc((size_t)E*8*4);
  unsigned short* hidb=(unsigned short*)alloc((size_t)(Epad+16)*64*2);
  unsigned short* w2t0=(unsigned short*)alloc((size_t)1088*64*2);
  unsigned short* w2t1=(unsigned short*)alloc((size_t)1088*64*2);
  unsigned short* hl16=(unsigned short*)alloc((size_t)N*512*2);
  float* combw=(float*)alloc((size_t)10*4096*4);
  float* bufB =(float*)alloc((size_t)N*512*4);
  float* bufC =(float*)alloc((size_t)N*512*4);
  float* e0b  =(float*)alloc((size_t)N*4);
  float* residb=(float*)alloc((size_t)N*32*4);

  dim3 tb(256);
  dim3 nblk((unsigned)((N*32+255)/256));
  dim3 n8blk((unsigned)((N+7)/8));
  dim3 eblk((unsigned)((E+255)/256));
  dim3 e16blk((unsigned)((E+15)/16));

  // CSR build (receiver-sorted edge order)
  hipMemsetAsync(deg,0,(size_t)N*4,stream);
  k_count<<<eblk,tb,0,stream>>>(rcv,deg,E);
  k_scan<<<dim3(1),dim3(1024),0,stream>>>(deg,rowp,cur,N);
  k_fill<<<eblk,tb,0,stream>>>(rcv,cur,eid,E);

  k_edge_setup<<<eblk,tb,0,stream>>>(vec,snd,rcv,eid,Yb,radb,snd_s,rcv_s,E);
  k_prep<<<dim3((2*1088*64+10*4096+255)/256),tb,0,stream>>>(r0w2,r1w2,w2t0,w2t1,post0,sel0,combw);
  k_embed16<<<nblk,tb,0,stream>>>(embed,up0,zarr,hl16,N);

  auto run_edges=[&](bool l0, const unsigned short* hlin, const unsigned short* w2t, float* agg){
    hipMemsetAsync(agg,0,(size_t)N*512*4,stream);
    if(l0) k_tp_fused<true ><<<e16blk,tb,0,stream>>>(hlin,Yb,hidb,w2t,snd_s,rcv_s,agg,0,E);
    else   k_tp_fused<false><<<e16blk,tb,0,stream>>>(hlin,Yb,hidb,w2t,snd_s,rcv_s,agg,0,E);
  };

  // ---- layer 0 ----
  k_radial<<<eblk,tb,0,stream>>>(radb,r0w0,r0w1,hidb,E);
  run_edges(true,hl16,w2t0,bufB);
  k_node0<<<n8blk,tb,0,stream>>>(bufB,combw,pb0,pblin0,ro0,res1,up1,zarr,e0b,residb,hl16,N);

  // ---- layer 1 ----
  k_radial<<<eblk,tb,0,stream>>>(radb,r1w0,r1w1,hidb,E);
  run_edges(false,hl16,w2t1,bufC);
  hipMemsetAsync(d_out,0,4,stream);
  k_node1<<<n8blk,tb,0,stream>>>(bufC,post1,pb1,pblin1,zarr,residb,e0b,ro1a,ro1b,(float*)d_out,N);
}